// Round 6
// baseline (419.032 us; speedup 1.0000x reference)
//
#include <hip/hip_runtime.h>
#include <hip/hip_bf16.h>
#include <stdint.h>

// Problem constants
#define L_DIM 1024
#define S_DIM 1024
#define N_DIM 8
#define E_DIM 1024
#define H_DIM 16
#define HD    64
#define BH    (N_DIM*H_DIM)    // 128 batch-heads
#define M_ROWS (L_DIM*N_DIM)   // 8192 rows for projection GEMMs

#define AS1 __attribute__((address_space(1)))
#define AS3 __attribute__((address_space(3)))

typedef __bf16 bf16x8 __attribute__((ext_vector_type(8)));
typedef float  f32x4  __attribute__((ext_vector_type(4)));
typedef unsigned short u16;
typedef unsigned short u16x8 __attribute__((ext_vector_type(8)));

// round-to-nearest-even f32 -> bf16 (finite inputs only)
__device__ inline u16 f2bf(float x){
  unsigned int u = __float_as_uint(x);
  u = (u + 0x7FFFu + ((u >> 16) & 1u)) >> 16;
  return (u16)u;
}

// ---------------------------------------------------------------------------
// Kernel 0: convert query, key, Wq (x0.125 folded), Wk to bf16 (vectorized x8)
// ---------------------------------------------------------------------------
__global__ __launch_bounds__(256) void convert_kernel(
    const float* __restrict__ query, const float* __restrict__ key,
    const float* __restrict__ w,
    u16* __restrict__ qbf, u16* __restrict__ kbf,
    u16* __restrict__ wq, u16* __restrict__ wk)
{
  const int QN = M_ROWS*E_DIM;   // 8388608
  const int WN = E_DIM*E_DIM;    // 1048576
  const int total8 = (2*QN + 2*WN)/8;
  int stride = gridDim.x*blockDim.x;
  for (int g = blockIdx.x*blockDim.x + threadIdx.x; g < total8; g += stride) {
    int base = g*8;
    const float* src; u16* dst; float scale = 1.0f;
    if (base < QN)           { src = query + base;      dst = qbf + base; }
    else if (base < 2*QN)    { src = key + (base-QN);   dst = kbf + (base-QN); }
    else if (base < 2*QN+WN) { src = w + (base-2*QN);   dst = wq + (base-2*QN); scale = 0.125f; }
    else                     { src = w + (base-2*QN);   dst = wk + (base-2*QN-WN); }
    float4 v0 = *(const float4*)(src);
    float4 v1 = *(const float4*)(src+4);
    u16x8 o;
    o[0]=f2bf(v0.x*scale); o[1]=f2bf(v0.y*scale); o[2]=f2bf(v0.z*scale); o[3]=f2bf(v0.w*scale);
    o[4]=f2bf(v1.x*scale); o[5]=f2bf(v1.y*scale); o[6]=f2bf(v1.z*scale); o[7]=f2bf(v1.w*scale);
    *(u16x8*)dst = o;
  }
}

// ---------------------------------------------------------------------------
// Kernel 1/2: projection GEMM, C = A @ W^T + bscale*bias, bf16 in, f32 acc.
// Output HEAD-MAJOR: C[(n*16+h)][l_or_s][d] -> contiguous 128 KB per head.
// (R3-proven form: two sequential launches.)
// ---------------------------------------------------------------------------
__global__ __launch_bounds__(256) void proj_gemm(
    const u16* __restrict__ A, const u16* __restrict__ W,
    const float* __restrict__ bias, float bscale,
    u16* __restrict__ C)
{
  __shared__ __align__(16) u16 As[128*32];
  __shared__ __align__(16) u16 Bs[128*32];
  const int t = threadIdx.x;
  const int lane = t & 63;
  const int w = t >> 6;
  const int wr = w >> 1, wc = w & 1;
  const int rowTile = blockIdx.x * 128;
  const int colTile = blockIdx.y * 128;

  f32x4 acc[4][4];
  #pragma unroll
  for (int m=0;m<4;m++)
    #pragma unroll
    for (int n=0;n<4;n++) acc[m][n] = (f32x4){0.f,0.f,0.f,0.f};

  uint32_t asBase = (uint32_t)(uintptr_t)&As[0];
  uint32_t bsBase = (uint32_t)(uintptr_t)&Bs[0];
  const char* Ab = (const char*)A;
  const char* Wb = (const char*)W;

  for (int kt = 0; kt < 32; ++kt) {
    __syncthreads();
    #pragma unroll
    for (int issue = 0; issue < 2; ++issue) {
      int o = issue*4096 + t*16;
      int row  = o >> 6;
      int colb = o & 63;
      const char* ga = Ab + (size_t)(rowTile + row)*2048 + kt*64 + colb;
      const char* gb = Wb + (size_t)(colTile + row)*2048 + kt*64 + colb;
      uint32_t la = asBase + issue*4096 + (w<<10);
      uint32_t lb = bsBase + issue*4096 + (w<<10);
      __builtin_amdgcn_global_load_lds(
          (const AS1 void*)(uintptr_t)ga, (AS3 void*)(uintptr_t)la, 16, 0, 0);
      __builtin_amdgcn_global_load_lds(
          (const AS1 void*)(uintptr_t)gb, (AS3 void*)(uintptr_t)lb, 16, 0, 0);
    }
    __syncthreads();

    bf16x8 af[4], bfr[4];
    int krow = (lane >> 4) * 16;
    #pragma unroll
    for (int m=0;m<4;m++) {
      int r = wr*64 + m*16 + (lane&15);
      af[m] = *(const bf16x8*)((const char*)As + r*64 + krow);
    }
    #pragma unroll
    for (int n=0;n<4;n++) {
      int r = wc*64 + n*16 + (lane&15);
      bfr[n] = *(const bf16x8*)((const char*)Bs + r*64 + krow);
    }
    #pragma unroll
    for (int m=0;m<4;m++)
      #pragma unroll
      for (int n=0;n<4;n++)
        acc[m][n] = __builtin_amdgcn_mfma_f32_16x16x32_bf16(af[m], bfr[n], acc[m][n], 0,0,0);
  }

  // epilogue -> head-major [n*16+h][l][d]; A row = l*8+n, col = h*64+d
  #pragma unroll
  for (int n2=0;n2<4;n2++) {
    int gcol = colTile + wc*64 + n2*16 + (lane&15);
    int h = gcol >> 6, d = gcol & 63;
    float bv = bias[gcol]*bscale;
    #pragma unroll
    for (int m=0;m<4;m++) {
      int grow0 = rowTile + wr*64 + m*16 + ((lane>>4)<<2);
      #pragma unroll
      for (int r=0;r<4;r++) {
        int grow = grow0 + r;
        int l = grow >> 3, nn = grow & 7;
        C[((size_t)(nn*16 + h)*1024 + l)*64 + d] = f2bf(acc[m][n2][r] + bv);
      }
    }
  }
}

// ---------------------------------------------------------------------------
// Kernel 3: fused QK^T + attn_bias + softmax — ALL-REGISTER scores.
// Block = 16 q-rows x one batch-head, 4 waves. Wave w owns s in
// [w*256, w*256+256). Swapped MFMA (A=K, B=Q): lane holds q = lane&15 and,
// per tile, 4 consecutive s -> 16x f32x4 acc = the lane's full 64-score row
// slice, kept in VGPRs end-to-end (no score LDS, no f16 roundtrip).
// Bias is the MFMA C-seed: acc = mfma(k1,q1, mfma(k0,q0, bias4)) -> the
// 537 MB bias stream is issued up-front and hidden under the MFMA loop
// (anti-convoy). Row max/sum: in-lane reduce + shfl_xor(16,32) + 512 B LDS
// cross-wave combine (2 barriers total). Output written from registers.
// ---------------------------------------------------------------------------
__global__ __launch_bounds__(256) void attn_softmax(
    const u16* __restrict__ Qh, const u16* __restrict__ Kh,
    const float* __restrict__ bias, float* __restrict__ out)
{
  __shared__ float red_max[4][16];
  __shared__ float red_sum[4][16];
  const int t = threadIdx.x;
  const int lane = t & 63;
  const int w = t >> 6;
  const int ltile = blockIdx.x;     // 64 tiles of 16 q-rows
  const int b = blockIdx.y;         // 128 batch-heads
  const int q  = lane & 15;
  const int sg = lane >> 4;

  // Q frag (B operand): row q, d = sg*8
  const u16* Qb = Qh + (size_t)b*65536 + (size_t)ltile*16*64;
  bf16x8 a0 = *(const bf16x8*)(Qb + q*64 + sg*8);
  bf16x8 a1 = *(const bf16x8*)(Qb + q*64 + sg*8 + 32);

  // K frags (A operand): s_local = lane&15, d = sg*8; tile st -> s = w*256+st*16+s_local
  const u16* Kw = Kh + (size_t)b*65536 + (size_t)w*16384 + (lane&15)*64 + sg*8;

  // bias/out per-lane row pointers: element s = w*256 + st*16 + sg*4 + r
  const size_t rowoff = (((size_t)b<<10) + (size_t)ltile*16 + q)*1024 + w*256 + sg*4;
  const float* bp = bias + rowoff;
  float*       op = out  + rowoff;

  // Seed accumulators with bias (issues the HBM read stream early)
  f32x4 acc[16];
  #pragma unroll
  for (int st = 0; st < 16; ++st)
    acc[st] = *(const f32x4*)(bp + st*16);

  // MFMA loop: acc[st] = K_tile^T Q + bias
  #pragma unroll
  for (int st = 0; st < 16; ++st) {
    const u16* kp = Kw + st*1024;
    bf16x8 k0 = *(const bf16x8*)kp;
    bf16x8 k1 = *(const bf16x8*)(kp + 32);
    acc[st] = __builtin_amdgcn_mfma_f32_16x16x32_bf16(k0, a0, acc[st], 0,0,0);
    acc[st] = __builtin_amdgcn_mfma_f32_16x16x32_bf16(k1, a1, acc[st], 0,0,0);
  }

  // Row max: in-lane (64 values) -> cross-lane (4 lanes share q) -> cross-wave
  float mx = fmaxf(fmaxf(acc[0][0], acc[0][1]), fmaxf(acc[0][2], acc[0][3]));
  #pragma unroll
  for (int st = 1; st < 16; ++st) {
    mx = fmaxf(mx, fmaxf(fmaxf(acc[st][0], acc[st][1]),
                         fmaxf(acc[st][2], acc[st][3])));
  }
  mx = fmaxf(mx, __shfl_xor(mx, 16, 64));
  mx = fmaxf(mx, __shfl_xor(mx, 32, 64));
  if (lane < 16) red_max[w][lane] = mx;
  __syncthreads();
  mx = fmaxf(fmaxf(red_max[0][q], red_max[1][q]),
             fmaxf(red_max[2][q], red_max[3][q]));

  // exp + sum
  float sum = 0.f;
  #pragma unroll
  for (int st = 0; st < 16; ++st) {
    #pragma unroll
    for (int r = 0; r < 4; ++r) {
      float e = __expf(acc[st][r] - mx);
      acc[st][r] = e;
      sum += e;
    }
  }
  sum += __shfl_xor(sum, 16, 64);
  sum += __shfl_xor(sum, 32, 64);
  if (lane < 16) red_sum[w][lane] = sum;
  __syncthreads();
  float inv = 1.0f / (red_sum[0][q] + red_sum[1][q] + red_sum[2][q] + red_sum[3][q]);

  // Write from registers
  #pragma unroll
  for (int st = 0; st < 16; ++st) {
    f32x4 o4 = { acc[st][0]*inv, acc[st][1]*inv, acc[st][2]*inv, acc[st][3]*inv };
    *(f32x4*)(op + st*16) = o4;
  }
}

// ---------------------------------------------------------------------------
// Workspace layout (68 MB total):
//   qbf 16 MB | kbf 16 MB | wq 2 MB | wk 2 MB | Qh 16 MB | Kh 16 MB
// ---------------------------------------------------------------------------
extern "C" void kernel_launch(void* const* d_in, const int* in_sizes, int n_in,
                              void* d_out, int out_size, void* d_ws, size_t ws_size,
                              hipStream_t stream) {
  const float* query = (const float*)d_in[0];
  const float* key   = (const float*)d_in[1];
  const float* w     = (const float*)d_in[2];
  const float* bias  = (const float*)d_in[3];
  const float* abias = (const float*)d_in[4];
  float* out = (float*)d_out;

  char* ws = (char*)d_ws;
  const size_t QKB = (size_t)M_ROWS*E_DIM*2;  // 16 MB
  const size_t WB  = (size_t)E_DIM*E_DIM*2;   // 2 MB
  u16* qbf = (u16*)ws;  ws += QKB;
  u16* kbf = (u16*)ws;  ws += QKB;
  u16* wq  = (u16*)ws;  ws += WB;
  u16* wk  = (u16*)ws;  ws += WB;
  u16* Qh  = (u16*)ws;  ws += QKB;   // head-major [bh][l][d]
  u16* Kh  = (u16*)ws;  ws += QKB;   // head-major [bh][s][d]

  hipLaunchKernelGGL(convert_kernel, dim3(2048), dim3(256), 0, stream,
                     query, key, w, qbf, kbf, wq, wk);
  hipLaunchKernelGGL(proj_gemm, dim3(64, 8), dim3(256), 0, stream,
                     qbf, wq, bias, 0.125f, Qh);
  hipLaunchKernelGGL(proj_gemm, dim3(64, 8), dim3(256), 0, stream,
                     kbf, wk, bias + 1024, 1.0f, Kh);
  hipLaunchKernelGGL(attn_softmax, dim3(64, 128), dim3(256), 0, stream,
                     Qh, Kh, abias, out);
}

// Round 7
// 348.731 us; speedup vs baseline: 1.2016x; 1.2016x over previous
//
#include <hip/hip_runtime.h>
#include <hip/hip_bf16.h>
#include <stdint.h>

// Problem constants
#define L_DIM 1024
#define S_DIM 1024
#define N_DIM 8
#define E_DIM 1024
#define H_DIM 16
#define HD    64
#define BH    (N_DIM*H_DIM)    // 128 batch-heads
#define M_ROWS (L_DIM*N_DIM)   // 8192 rows for projection GEMMs

#define AS1 __attribute__((address_space(1)))
#define AS3 __attribute__((address_space(3)))

typedef __bf16 bf16x8 __attribute__((ext_vector_type(8)));
typedef float  f32x4  __attribute__((ext_vector_type(4)));
typedef _Float16 f16;
typedef _Float16 f16x8 __attribute__((ext_vector_type(8)));
typedef unsigned short u16;
typedef unsigned short u16x8 __attribute__((ext_vector_type(8)));

// round-to-nearest-even f32 -> bf16 (finite inputs only)
__device__ inline u16 f2bf(float x){
  unsigned int u = __float_as_uint(x);
  u = (u + 0x7FFFu + ((u >> 16) & 1u)) >> 16;
  return (u16)u;
}

// ---------------------------------------------------------------------------
// Kernel 0: convert query, key, Wq (x0.125 folded), Wk to bf16 (vectorized x8)
// ---------------------------------------------------------------------------
__global__ __launch_bounds__(256) void convert_kernel(
    const float* __restrict__ query, const float* __restrict__ key,
    const float* __restrict__ w,
    u16* __restrict__ qbf, u16* __restrict__ kbf,
    u16* __restrict__ wq, u16* __restrict__ wk)
{
  const int QN = M_ROWS*E_DIM;   // 8388608
  const int WN = E_DIM*E_DIM;    // 1048576
  const int total8 = (2*QN + 2*WN)/8;
  int stride = gridDim.x*blockDim.x;
  for (int g = blockIdx.x*blockDim.x + threadIdx.x; g < total8; g += stride) {
    int base = g*8;
    const float* src; u16* dst; float scale = 1.0f;
    if (base < QN)           { src = query + base;      dst = qbf + base; }
    else if (base < 2*QN)    { src = key + (base-QN);   dst = kbf + (base-QN); }
    else if (base < 2*QN+WN) { src = w + (base-2*QN);   dst = wq + (base-2*QN); scale = 0.125f; }
    else                     { src = w + (base-2*QN);   dst = wk + (base-2*QN-WN); }
    float4 v0 = *(const float4*)(src);
    float4 v1 = *(const float4*)(src+4);
    u16x8 o;
    o[0]=f2bf(v0.x*scale); o[1]=f2bf(v0.y*scale); o[2]=f2bf(v0.z*scale); o[3]=f2bf(v0.w*scale);
    o[4]=f2bf(v1.x*scale); o[5]=f2bf(v1.y*scale); o[6]=f2bf(v1.z*scale); o[7]=f2bf(v1.w*scale);
    *(u16x8*)dst = o;
  }
}

// ---------------------------------------------------------------------------
// Kernel 1/2: projection GEMM, C = A @ W^T + bscale*bias, bf16 in, f32 acc.
// Output HEAD-MAJOR: C[(n*16+h)][l_or_s][d] -> contiguous 128 KB per head.
// (R3-proven form: two sequential launches.)
// ---------------------------------------------------------------------------
__global__ __launch_bounds__(256) void proj_gemm(
    const u16* __restrict__ A, const u16* __restrict__ W,
    const float* __restrict__ bias, float bscale,
    u16* __restrict__ C)
{
  __shared__ __align__(16) u16 As[128*32];
  __shared__ __align__(16) u16 Bs[128*32];
  const int t = threadIdx.x;
  const int lane = t & 63;
  const int w = t >> 6;
  const int wr = w >> 1, wc = w & 1;
  const int rowTile = blockIdx.x * 128;
  const int colTile = blockIdx.y * 128;

  f32x4 acc[4][4];
  #pragma unroll
  for (int m=0;m<4;m++)
    #pragma unroll
    for (int n=0;n<4;n++) acc[m][n] = (f32x4){0.f,0.f,0.f,0.f};

  uint32_t asBase = (uint32_t)(uintptr_t)&As[0];
  uint32_t bsBase = (uint32_t)(uintptr_t)&Bs[0];
  const char* Ab = (const char*)A;
  const char* Wb = (const char*)W;

  for (int kt = 0; kt < 32; ++kt) {
    __syncthreads();
    #pragma unroll
    for (int issue = 0; issue < 2; ++issue) {
      int o = issue*4096 + t*16;
      int row  = o >> 6;
      int colb = o & 63;
      const char* ga = Ab + (size_t)(rowTile + row)*2048 + kt*64 + colb;
      const char* gb = Wb + (size_t)(colTile + row)*2048 + kt*64 + colb;
      uint32_t la = asBase + issue*4096 + (w<<10);
      uint32_t lb = bsBase + issue*4096 + (w<<10);
      __builtin_amdgcn_global_load_lds(
          (const AS1 void*)(uintptr_t)ga, (AS3 void*)(uintptr_t)la, 16, 0, 0);
      __builtin_amdgcn_global_load_lds(
          (const AS1 void*)(uintptr_t)gb, (AS3 void*)(uintptr_t)lb, 16, 0, 0);
    }
    __syncthreads();

    bf16x8 af[4], bfr[4];
    int krow = (lane >> 4) * 16;
    #pragma unroll
    for (int m=0;m<4;m++) {
      int r = wr*64 + m*16 + (lane&15);
      af[m] = *(const bf16x8*)((const char*)As + r*64 + krow);
    }
    #pragma unroll
    for (int n=0;n<4;n++) {
      int r = wc*64 + n*16 + (lane&15);
      bfr[n] = *(const bf16x8*)((const char*)Bs + r*64 + krow);
    }
    #pragma unroll
    for (int m=0;m<4;m++)
      #pragma unroll
      for (int n=0;n<4;n++)
        acc[m][n] = __builtin_amdgcn_mfma_f32_16x16x32_bf16(af[m], bfr[n], acc[m][n], 0,0,0);
  }

  // epilogue -> head-major [n*16+h][l][d]; A row = l*8+n, col = h*64+d
  #pragma unroll
  for (int n2=0;n2<4;n2++) {
    int gcol = colTile + wc*64 + n2*16 + (lane&15);
    int h = gcol >> 6, d = gcol & 63;
    float bv = bias[gcol]*bscale;
    #pragma unroll
    for (int m=0;m<4;m++) {
      int grow0 = rowTile + wr*64 + m*16 + ((lane>>4)<<2);
      #pragma unroll
      for (int r=0;r<4;r++) {
        int grow = grow0 + r;
        int l = grow >> 3, nn = grow & 7;
        C[((size_t)(nn*16 + h)*1024 + l)*64 + d] = f2bf(acc[m][n2][r] + bv);
      }
    }
  }
}

// ---------------------------------------------------------------------------
// Kernel 3: fused QK^T + attn_bias + softmax (R3 structure + bias prefetch).
// Block = 16 q-rows x one batch-head, 4 waves, 40 KB LDS.
// NEW: the block's 64 KB bias slice is loaded into REGISTERS at kernel entry
// (16x f32x4 per thread, statically indexed, pinned above phase 1 via
// sched_barrier) so the 537 MB bias read stream overlaps the K-staging/MFMA
// phase instead of serializing into phase 2. Phase 2 is then LDS + VALU +
// a pure coalesced write stream.
// Phase 1: K staged through 8 KB LDS chunks via coalesced global_load_lds
//   (linear dest + involution-swizzled source; swizzled ds_read), wave w
//   computes s-tile g*4+w per chunk, scores -> f16 LDS (32 KB, row-swizzled).
// Phase 2: wave-per-row softmax; bias from registers; f32x4 out writes.
// ---------------------------------------------------------------------------
__global__ __launch_bounds__(256) void attn_softmax(
    const u16* __restrict__ Qh, const u16* __restrict__ Kh,
    const float* __restrict__ bias, float* __restrict__ out)
{
  __shared__ __align__(16) char scb[16*2048];    // 32 KB f16 scores, swizzled
  __shared__ __align__(16) char kbuf[8192];      // 64 s-rows x 64 d, swizzled
  const int t = threadIdx.x;
  const int lane = t & 63;
  const int w = t >> 6;
  const int ltile = blockIdx.x;     // 64 tiles of 16 q-rows
  const int b = blockIdx.y;         // 128 batch-heads

  // ---- bias prefetch into registers (issues the HBM read stream NOW) ----
  // Thread's phase-2 ownership: rows {w, w+4, w+8, w+12}, 16 floats per row
  // at cols it*512 + lane*8 (+4). 4 rows x 4 f32x4 = 64 VGPRs.
  const float* bias_base = bias + (((size_t)b<<10) + (size_t)ltile*16)*1024;
  f32x4 breg[4][4];
  #pragma unroll
  for (int rr=0;rr<4;rr++) {
    const float* brow = bias_base + (size_t)(rr*4 + w)*1024 + lane*8;
    #pragma unroll
    for (int p=0;p<4;p++)
      breg[rr][p] = *(const f32x4*)(brow + (p>>1)*512 + (p&1)*4);
  }
  __builtin_amdgcn_sched_barrier(0);   // keep the loads above phase 1

  const char* Kb = (const char*)(Kh + (size_t)b*1024*64);               // 128 KB
  const u16*  Qb = Qh + (size_t)b*1024*64 + (size_t)ltile*16*64;        // 2 KB

  // A-frags: q-row = lane&15 (row stride 128 B), d = (lane>>4)*8
  int qoff = (lane&15)*64 + (lane>>4)*8;
  bf16x8 a0 = *(const bf16x8*)(Qb + qoff);
  bf16x8 a1 = *(const bf16x8*)(Qb + qoff + 32);

  const int rowBase = (lane>>4)*4;
  uint32_t kbase = (uint32_t)(uintptr_t)&kbuf[0];

  for (int g = 0; g < 16; ++g) {
    __syncthreads();   // previous chunk's readers done before overwrite
    #pragma unroll
    for (int rd = 0; rd < 2; ++rd) {
      int o = rd*4096 + t*16;                    // linear LDS byte offset
      int src = o ^ (((o>>7)&7)<<4);             // inverse swizzle (involution)
      __builtin_amdgcn_global_load_lds(
          (const AS1 void*)(uintptr_t)(Kb + (size_t)g*8192 + src),
          (AS3 void*)(uintptr_t)(kbase + rd*4096 + (w<<10)), 16, 0, 0);
    }
    __syncthreads();   // staging visible (compiler drains vmcnt before barrier)

    // wave w: s-tile st = g*4+w, local rows r = w*16 + (lane&15)
    int r = w*16 + (lane&15);
    int byte0 = r*128 + ((lane>>4)*16);
    int swzk = (r&7)<<4;
    bf16x8 b0 = *(const bf16x8*)(kbuf + ((byte0      ) ^ swzk));
    bf16x8 b1 = *(const bf16x8*)(kbuf + ((byte0 + 64 ) ^ swzk));
    f32x4 acc = {0.f,0.f,0.f,0.f};
    acc = __builtin_amdgcn_mfma_f32_16x16x32_bf16(a0, b0, acc, 0,0,0);
    acc = __builtin_amdgcn_mfma_f32_16x16x32_bf16(a1, b1, acc, 0,0,0);

    int scol = g*64 + w*16 + (lane & 15);        // global s index
    #pragma unroll
    for (int rr=0;rr<4;rr++) {
      int row = rowBase + rr;
      int byte = (row*2048 + scol*2) ^ ((row&7)<<4);
      *(f16*)(scb + byte) = (f16)acc[rr];
    }
  }
  __syncthreads();

  // Phase 2: wave w owns rows {w, w+4, w+8, w+12}; bias already in registers.
  #pragma unroll
  for (int rr=0;rr<4;rr++) {
    int row = rr*4 + w;
    int l_glob = ltile*16 + row;
    float* orow = out + ((size_t)b*1024 + l_glob)*1024;
    const int rswz = (row&7)<<4;
    float v[16];
    float mx = -1e30f;
    #pragma unroll
    for (int it=0; it<2; ++it) {
      int cb = it*1024 + lane*16;                 // logical byte offset in row
      f16x8 s8 = *(const f16x8*)(scb + ((row*2048 + cb) ^ rswz));
      #pragma unroll
      for (int j=0;j<4;j++) v[it*8+j]   = (float)s8[j]   + breg[rr][it*2][j];
      #pragma unroll
      for (int j=0;j<4;j++) v[it*8+4+j] = (float)s8[4+j] + breg[rr][it*2+1][j];
    }
    #pragma unroll
    for (int j=0;j<16;j++) mx = fmaxf(mx, v[j]);
    #pragma unroll
    for (int off=32; off>0; off>>=1) mx = fmaxf(mx, __shfl_xor(mx, off, 64));
    float sum = 0.f;
    #pragma unroll
    for (int j=0;j<16;j++) { v[j] = __expf(v[j]-mx); sum += v[j]; }
    #pragma unroll
    for (int off=32; off>0; off>>=1) sum += __shfl_xor(sum, off, 64);
    float inv = 1.0f / sum;
    #pragma unroll
    for (int it=0; it<2; ++it) {
      int col = it*512 + lane*8;
      f32x4 o4a = { v[it*8+0]*inv, v[it*8+1]*inv, v[it*8+2]*inv, v[it*8+3]*inv };
      f32x4 o4b = { v[it*8+4]*inv, v[it*8+5]*inv, v[it*8+6]*inv, v[it*8+7]*inv };
      *(f32x4*)(orow + col)     = o4a;
      *(f32x4*)(orow + col + 4) = o4b;
    }
  }
}

// ---------------------------------------------------------------------------
// Workspace layout (68 MB total):
//   qbf 16 MB | kbf 16 MB | wq 2 MB | wk 2 MB | Qh 16 MB | Kh 16 MB
// ---------------------------------------------------------------------------
extern "C" void kernel_launch(void* const* d_in, const int* in_sizes, int n_in,
                              void* d_out, int out_size, void* d_ws, size_t ws_size,
                              hipStream_t stream) {
  const float* query = (const float*)d_in[0];
  const float* key   = (const float*)d_in[1];
  const float* w     = (const float*)d_in[2];
  const float* bias  = (const float*)d_in[3];
  const float* abias = (const float*)d_in[4];
  float* out = (float*)d_out;

  char* ws = (char*)d_ws;
  const size_t QKB = (size_t)M_ROWS*E_DIM*2;  // 16 MB
  const size_t WB  = (size_t)E_DIM*E_DIM*2;   // 2 MB
  u16* qbf = (u16*)ws;  ws += QKB;
  u16* kbf = (u16*)ws;  ws += QKB;
  u16* wq  = (u16*)ws;  ws += WB;
  u16* wk  = (u16*)ws;  ws += WB;
  u16* Qh  = (u16*)ws;  ws += QKB;   // head-major [bh][l][d]
  u16* Kh  = (u16*)ws;  ws += QKB;   // head-major [bh][s][d]

  hipLaunchKernelGGL(convert_kernel, dim3(2048), dim3(256), 0, stream,
                     query, key, w, qbf, kbf, wq, wk);
  hipLaunchKernelGGL(proj_gemm, dim3(64, 8), dim3(256), 0, stream,
                     qbf, wq, bias, 0.125f, Qh);
  hipLaunchKernelGGL(proj_gemm, dim3(64, 8), dim3(256), 0, stream,
                     kbf, wk, bias + 1024, 1.0f, Kh);
  hipLaunchKernelGGL(attn_softmax, dim3(64, 128), dim3(256), 0, stream,
                     Qh, Kh, abias, out);
}

// Round 8
// 345.521 us; speedup vs baseline: 1.2128x; 1.0093x over previous
//
#include <hip/hip_runtime.h>
#include <hip/hip_bf16.h>
#include <stdint.h>

// Problem constants
#define L_DIM 1024
#define S_DIM 1024
#define N_DIM 8
#define E_DIM 1024
#define H_DIM 16
#define HD    64
#define BH    (N_DIM*H_DIM)    // 128 batch-heads
#define M_ROWS (L_DIM*N_DIM)   // 8192 rows for projection GEMMs

#define AS1 __attribute__((address_space(1)))
#define AS3 __attribute__((address_space(3)))

typedef __bf16 bf16x8 __attribute__((ext_vector_type(8)));
typedef float  f32x4  __attribute__((ext_vector_type(4)));
typedef _Float16 f16;
typedef _Float16 f16x8 __attribute__((ext_vector_type(8)));
typedef unsigned short u16;
typedef unsigned short u16x8 __attribute__((ext_vector_type(8)));

// round-to-nearest-even f32 -> bf16 (finite inputs only)
__device__ inline u16 f2bf(float x){
  unsigned int u = __float_as_uint(x);
  u = (u + 0x7FFFu + ((u >> 16) & 1u)) >> 16;
  return (u16)u;
}

// ---------------------------------------------------------------------------
// Kernel 0: convert query, key, Wq (x0.125 folded), Wk to bf16 (vectorized x8)
// ---------------------------------------------------------------------------
__global__ __launch_bounds__(256) void convert_kernel(
    const float* __restrict__ query, const float* __restrict__ key,
    const float* __restrict__ w,
    u16* __restrict__ qbf, u16* __restrict__ kbf,
    u16* __restrict__ wq, u16* __restrict__ wk)
{
  const int QN = M_ROWS*E_DIM;   // 8388608
  const int WN = E_DIM*E_DIM;    // 1048576
  const int total8 = (2*QN + 2*WN)/8;
  int stride = gridDim.x*blockDim.x;
  for (int g = blockIdx.x*blockDim.x + threadIdx.x; g < total8; g += stride) {
    int base = g*8;
    const float* src; u16* dst; float scale = 1.0f;
    if (base < QN)           { src = query + base;      dst = qbf + base; }
    else if (base < 2*QN)    { src = key + (base-QN);   dst = kbf + (base-QN); }
    else if (base < 2*QN+WN) { src = w + (base-2*QN);   dst = wq + (base-2*QN); scale = 0.125f; }
    else                     { src = w + (base-2*QN);   dst = wk + (base-2*QN-WN); }
    float4 v0 = *(const float4*)(src);
    float4 v1 = *(const float4*)(src+4);
    u16x8 o;
    o[0]=f2bf(v0.x*scale); o[1]=f2bf(v0.y*scale); o[2]=f2bf(v0.z*scale); o[3]=f2bf(v0.w*scale);
    o[4]=f2bf(v1.x*scale); o[5]=f2bf(v1.y*scale); o[6]=f2bf(v1.z*scale); o[7]=f2bf(v1.w*scale);
    *(u16x8*)dst = o;
  }
}

// ---------------------------------------------------------------------------
// Kernel 1/2: projection GEMM, C = A @ W^T + bscale*bias, bf16 in, f32 acc.
// Output HEAD-MAJOR: C[(n*16+h)][l_or_s][d] -> contiguous 128 KB per head.
// (R3-proven form: two sequential launches.)
// ---------------------------------------------------------------------------
__global__ __launch_bounds__(256) void proj_gemm(
    const u16* __restrict__ A, const u16* __restrict__ W,
    const float* __restrict__ bias, float bscale,
    u16* __restrict__ C)
{
  __shared__ __align__(16) u16 As[128*32];
  __shared__ __align__(16) u16 Bs[128*32];
  const int t = threadIdx.x;
  const int lane = t & 63;
  const int w = t >> 6;
  const int wr = w >> 1, wc = w & 1;
  const int rowTile = blockIdx.x * 128;
  const int colTile = blockIdx.y * 128;

  f32x4 acc[4][4];
  #pragma unroll
  for (int m=0;m<4;m++)
    #pragma unroll
    for (int n=0;n<4;n++) acc[m][n] = (f32x4){0.f,0.f,0.f,0.f};

  uint32_t asBase = (uint32_t)(uintptr_t)&As[0];
  uint32_t bsBase = (uint32_t)(uintptr_t)&Bs[0];
  const char* Ab = (const char*)A;
  const char* Wb = (const char*)W;

  for (int kt = 0; kt < 32; ++kt) {
    __syncthreads();
    #pragma unroll
    for (int issue = 0; issue < 2; ++issue) {
      int o = issue*4096 + t*16;
      int row  = o >> 6;
      int colb = o & 63;
      const char* ga = Ab + (size_t)(rowTile + row)*2048 + kt*64 + colb;
      const char* gb = Wb + (size_t)(colTile + row)*2048 + kt*64 + colb;
      uint32_t la = asBase + issue*4096 + (w<<10);
      uint32_t lb = bsBase + issue*4096 + (w<<10);
      __builtin_amdgcn_global_load_lds(
          (const AS1 void*)(uintptr_t)ga, (AS3 void*)(uintptr_t)la, 16, 0, 0);
      __builtin_amdgcn_global_load_lds(
          (const AS1 void*)(uintptr_t)gb, (AS3 void*)(uintptr_t)lb, 16, 0, 0);
    }
    __syncthreads();

    bf16x8 af[4], bfr[4];
    int krow = (lane >> 4) * 16;
    #pragma unroll
    for (int m=0;m<4;m++) {
      int r = wr*64 + m*16 + (lane&15);
      af[m] = *(const bf16x8*)((const char*)As + r*64 + krow);
    }
    #pragma unroll
    for (int n=0;n<4;n++) {
      int r = wc*64 + n*16 + (lane&15);
      bfr[n] = *(const bf16x8*)((const char*)Bs + r*64 + krow);
    }
    #pragma unroll
    for (int m=0;m<4;m++)
      #pragma unroll
      for (int n=0;n<4;n++)
        acc[m][n] = __builtin_amdgcn_mfma_f32_16x16x32_bf16(af[m], bfr[n], acc[m][n], 0,0,0);
  }

  // epilogue -> head-major [n*16+h][l][d]; A row = l*8+n, col = h*64+d
  #pragma unroll
  for (int n2=0;n2<4;n2++) {
    int gcol = colTile + wc*64 + n2*16 + (lane&15);
    int h = gcol >> 6, d = gcol & 63;
    float bv = bias[gcol]*bscale;
    #pragma unroll
    for (int m=0;m<4;m++) {
      int grow0 = rowTile + wr*64 + m*16 + ((lane>>4)<<2);
      #pragma unroll
      for (int r=0;r<4;r++) {
        int grow = grow0 + r;
        int l = grow >> 3, nn = grow & 7;
        C[((size_t)(nn*16 + h)*1024 + l)*64 + d] = f2bf(acc[m][n2][r] + bv);
      }
    }
  }
}

// ---------------------------------------------------------------------------
// Kernel 3: fused QK^T + attn_bias + softmax — wave-decoupled pipeline.
// Block = 16 q-rows x one batch-head, 4 waves, 48 KB LDS.
// Phase 1 has ZERO barriers: each wave stages its own 16 K-rows per chunk
// (wave-private 2 KB x2 dbuf via global_load_lds, involution-swizzled src),
// pipelined with counted s_waitcnt vmcnt(6). Bias enters as the MFMA C-seed
// (4 coalesced scalar f32 loads/lane/chunk, also in the vmcnt pipeline) so
// the 537 MB bias stream overlaps compute chunk-by-chunk (anti-convoy).
// Scores (bias included) -> f16 LDS (32 KB, row-XOR-swizzled).
// Phase 2 (after the single __syncthreads): wave-per-row softmax, pure
// coalesced f32x4 write stream (no global reads).
// ---------------------------------------------------------------------------
__global__ __launch_bounds__(256) void attn_softmax(
    const u16* __restrict__ Qh, const u16* __restrict__ Kh,
    const float* __restrict__ bias, float* __restrict__ out)
{
  __shared__ __align__(16) char scb[16*2048];      // 32 KB f16 scores, swizzled
  __shared__ __align__(16) char kbuf[2][4][2048];  // 16 KB: dbuf x wave x 16 rows
  const int t = threadIdx.x;
  const int lane = t & 63;
  const int w = t >> 6;
  const int ltile = blockIdx.x;     // 64 tiles of 16 q-rows
  const int b = blockIdx.y;         // 128 batch-heads
  const int q16 = lane & 15;
  const int sg  = lane >> 4;

  const char* Kb = (const char*)(Kh + (size_t)b*65536);
  const u16*  Qb = Qh + (size_t)b*65536 + (size_t)ltile*1024;   // 16 rows x 64

  // Q frags (A operand): q-row = q16, d = sg*8
  bf16x8 a0 = *(const bf16x8*)(Qb + q16*64 + sg*8);
  bf16x8 a1 = *(const bf16x8*)(Qb + q16*64 + sg*8 + 32);

  // Wave-private K staging: lane l covers LDS bytes l*16 of each 1 KB half.
  // LDS byte o (in 2KB wave buf): row = o>>7, col = o&127; stored swizzled:
  // src_global_col = col ^ ((row&7)<<4). Closed form per lane:
  const int stg_row = lane >> 3;                         // 0..7
  const int stg_off = (((lane & 7) ^ stg_row) << 4);     // pre-swizzled col
  const char* Kst = Kb + w*2048 + stg_row*128 + stg_off; // + g*8192 (+1024 for half 1)
  const uint32_t kw0 = (uint32_t)(uintptr_t)&kbuf[0][w][0];
  const uint32_t kw1 = (uint32_t)(uintptr_t)&kbuf[1][w][0];

  // Bias per-lane base: rows q = sg*4 + rr, col s = g*64 + w*16 + q16
  const float* bl = bias + ((size_t)b*1024 + ltile*16 + sg*4)*1024 + w*16 + q16;

  float bv[2][4];

  #define ISSUE_CHUNK(gg, dd) do {                                          \
    const char* s_ = Kst + (gg)*8192;                                       \
    uint32_t d_ = (dd) ? kw1 : kw0;                                         \
    __builtin_amdgcn_global_load_lds(                                       \
        (const AS1 void*)(uintptr_t)s_, (AS3 void*)(uintptr_t)d_, 16, 0, 0);\
    __builtin_amdgcn_global_load_lds(                                       \
        (const AS1 void*)(uintptr_t)(s_+1024),                              \
        (AS3 void*)(uintptr_t)(d_+1024), 16, 0, 0);                         \
    bv[dd][0] = bl[(gg)*64];                                                \
    bv[dd][1] = bl[(gg)*64 + 1024];                                         \
    bv[dd][2] = bl[(gg)*64 + 2048];                                         \
    bv[dd][3] = bl[(gg)*64 + 3072];                                         \
  } while(0)

  ISSUE_CHUNK(0, 0);   // prologue

  const int c0 = ((sg     ^ (q16 & 7)) << 4);
  const int c1 = (((4+sg) ^ (q16 & 7)) << 4);

  #pragma unroll
  for (int g = 0; g < 16; ++g) {
    const int d = g & 1;
    if (g < 15) ISSUE_CHUNK(g+1, d^1);
    if (g < 15) { asm volatile("s_waitcnt vmcnt(6)" ::: "memory"); }
    else        { asm volatile("s_waitcnt vmcnt(0)" ::: "memory"); }
    __builtin_amdgcn_sched_barrier(0);

    const char* kw = (const char*)&kbuf[d][w][0];
    bf16x8 b0 = *(const bf16x8*)(kw + q16*128 + c0);
    bf16x8 b1 = *(const bf16x8*)(kw + q16*128 + c1);
    f32x4 acc = { bv[d][0], bv[d][1], bv[d][2], bv[d][3] };
    acc = __builtin_amdgcn_mfma_f32_16x16x32_bf16(a0, b0, acc, 0,0,0);
    acc = __builtin_amdgcn_mfma_f32_16x16x32_bf16(a1, b1, acc, 0,0,0);

    const int scol = g*64 + w*16 + q16;
    #pragma unroll
    for (int rr=0; rr<4; ++rr) {
      int row = sg*4 + rr;
      int byte = (row*2048 + scol*2) ^ ((row&7)<<4);
      *(f16*)(scb + byte) = (f16)acc[rr];
    }
    __builtin_amdgcn_sched_barrier(0);  // pin: next issues after this compute
  }
  #undef ISSUE_CHUNK

  __syncthreads();

  // Phase 2: wave w owns rows {w, w+4, w+8, w+12}; scores already biased.
  #pragma unroll
  for (int rr=0;rr<4;rr++) {
    int row = rr*4 + w;
    int l_glob = ltile*16 + row;
    float* orow = out + ((size_t)b*1024 + l_glob)*1024;
    const int rswz = (row&7)<<4;
    float v[16];
    float mx = -1e30f;
    #pragma unroll
    for (int it=0; it<2; ++it) {
      int cb = it*1024 + lane*16;                 // logical byte offset in row
      f16x8 s8 = *(const f16x8*)(scb + ((row*2048 + cb) ^ rswz));
      #pragma unroll
      for (int j=0;j<8;j++) v[it*8+j] = (float)s8[j];
    }
    #pragma unroll
    for (int j=0;j<16;j++) mx = fmaxf(mx, v[j]);
    #pragma unroll
    for (int off=32; off>0; off>>=1) mx = fmaxf(mx, __shfl_xor(mx, off, 64));
    float sum = 0.f;
    #pragma unroll
    for (int j=0;j<16;j++) { v[j] = __expf(v[j]-mx); sum += v[j]; }
    #pragma unroll
    for (int off=32; off>0; off>>=1) sum += __shfl_xor(sum, off, 64);
    float inv = 1.0f / sum;
    #pragma unroll
    for (int it=0; it<2; ++it) {
      int col = it*512 + lane*8;
      f32x4 o4a = { v[it*8+0]*inv, v[it*8+1]*inv, v[it*8+2]*inv, v[it*8+3]*inv };
      f32x4 o4b = { v[it*8+4]*inv, v[it*8+5]*inv, v[it*8+6]*inv, v[it*8+7]*inv };
      *(f32x4*)(orow + col)     = o4a;
      *(f32x4*)(orow + col + 4) = o4b;
    }
  }
}

// ---------------------------------------------------------------------------
// Workspace layout (68 MB total):
//   qbf 16 MB | kbf 16 MB | wq 2 MB | wk 2 MB | Qh 16 MB | Kh 16 MB
// ---------------------------------------------------------------------------
extern "C" void kernel_launch(void* const* d_in, const int* in_sizes, int n_in,
                              void* d_out, int out_size, void* d_ws, size_t ws_size,
                              hipStream_t stream) {
  const float* query = (const float*)d_in[0];
  const float* key   = (const float*)d_in[1];
  const float* w     = (const float*)d_in[2];
  const float* bias  = (const float*)d_in[3];
  const float* abias = (const float*)d_in[4];
  float* out = (float*)d_out;

  char* ws = (char*)d_ws;
  const size_t QKB = (size_t)M_ROWS*E_DIM*2;  // 16 MB
  const size_t WB  = (size_t)E_DIM*E_DIM*2;   // 2 MB
  u16* qbf = (u16*)ws;  ws += QKB;
  u16* kbf = (u16*)ws;  ws += QKB;
  u16* wq  = (u16*)ws;  ws += WB;
  u16* wk  = (u16*)ws;  ws += WB;
  u16* Qh  = (u16*)ws;  ws += QKB;   // head-major [bh][l][d]
  u16* Kh  = (u16*)ws;  ws += QKB;   // head-major [bh][s][d]

  hipLaunchKernelGGL(convert_kernel, dim3(2048), dim3(256), 0, stream,
                     query, key, w, qbf, kbf, wq, wk);
  hipLaunchKernelGGL(proj_gemm, dim3(64, 8), dim3(256), 0, stream,
                     qbf, wq, bias, 0.125f, Qh);
  hipLaunchKernelGGL(proj_gemm, dim3(64, 8), dim3(256), 0, stream,
                     kbf, wk, bias + 1024, 1.0f, Kh);
  hipLaunchKernelGGL(attn_softmax, dim3(64, 128), dim3(256), 0, stream,
                     Qh, Kh, abias, out);
}

// Round 9
// 345.456 us; speedup vs baseline: 1.2130x; 1.0002x over previous
//
#include <hip/hip_runtime.h>
#include <hip/hip_bf16.h>
#include <stdint.h>

// Problem constants
#define L_DIM 1024
#define S_DIM 1024
#define N_DIM 8
#define E_DIM 1024
#define H_DIM 16
#define HD    64
#define BH    (N_DIM*H_DIM)    // 128 batch-heads
#define M_ROWS (L_DIM*N_DIM)   // 8192 rows for projection GEMMs

#define AS1 __attribute__((address_space(1)))
#define AS3 __attribute__((address_space(3)))

typedef __bf16 bf16x8 __attribute__((ext_vector_type(8)));
typedef float  f32x4  __attribute__((ext_vector_type(4)));
typedef _Float16 f16;
typedef _Float16 f16x8 __attribute__((ext_vector_type(8)));
typedef unsigned short u16;
typedef unsigned short u16x8 __attribute__((ext_vector_type(8)));

// round-to-nearest-even f32 -> bf16 (finite inputs only)
__device__ inline u16 f2bf(float x){
  unsigned int u = __float_as_uint(x);
  u = (u + 0x7FFFu + ((u >> 16) & 1u)) >> 16;
  return (u16)u;
}

// ---------------------------------------------------------------------------
// Kernel 0: convert query, key, Wq (x0.125 folded), Wk to bf16 (vectorized x8)
// ---------------------------------------------------------------------------
__global__ __launch_bounds__(256) void convert_kernel(
    const float* __restrict__ query, const float* __restrict__ key,
    const float* __restrict__ w,
    u16* __restrict__ qbf, u16* __restrict__ kbf,
    u16* __restrict__ wq, u16* __restrict__ wk)
{
  const int QN = M_ROWS*E_DIM;   // 8388608
  const int WN = E_DIM*E_DIM;    // 1048576
  const int total8 = (2*QN + 2*WN)/8;
  int stride = gridDim.x*blockDim.x;
  for (int g = blockIdx.x*blockDim.x + threadIdx.x; g < total8; g += stride) {
    int base = g*8;
    const float* src; u16* dst; float scale = 1.0f;
    if (base < QN)           { src = query + base;      dst = qbf + base; }
    else if (base < 2*QN)    { src = key + (base-QN);   dst = kbf + (base-QN); }
    else if (base < 2*QN+WN) { src = w + (base-2*QN);   dst = wq + (base-2*QN); scale = 0.125f; }
    else                     { src = w + (base-2*QN);   dst = wk + (base-2*QN-WN); }
    float4 v0 = *(const float4*)(src);
    float4 v1 = *(const float4*)(src+4);
    u16x8 o;
    o[0]=f2bf(v0.x*scale); o[1]=f2bf(v0.y*scale); o[2]=f2bf(v0.z*scale); o[3]=f2bf(v0.w*scale);
    o[4]=f2bf(v1.x*scale); o[5]=f2bf(v1.y*scale); o[6]=f2bf(v1.z*scale); o[7]=f2bf(v1.w*scale);
    *(u16x8*)dst = o;
  }
}

// ---------------------------------------------------------------------------
// Kernel 1/2: projection GEMM, C = A @ W^T + bscale*bias, bf16 in, f32 acc.
// Output HEAD-MAJOR: C[(n*16+h)][l_or_s][d] -> contiguous 128 KB per head.
// (R3-proven form: two sequential launches.)
// ---------------------------------------------------------------------------
__global__ __launch_bounds__(256) void proj_gemm(
    const u16* __restrict__ A, const u16* __restrict__ W,
    const float* __restrict__ bias, float bscale,
    u16* __restrict__ C)
{
  __shared__ __align__(16) u16 As[128*32];
  __shared__ __align__(16) u16 Bs[128*32];
  const int t = threadIdx.x;
  const int lane = t & 63;
  const int w = t >> 6;
  const int wr = w >> 1, wc = w & 1;
  const int rowTile = blockIdx.x * 128;
  const int colTile = blockIdx.y * 128;

  f32x4 acc[4][4];
  #pragma unroll
  for (int m=0;m<4;m++)
    #pragma unroll
    for (int n=0;n<4;n++) acc[m][n] = (f32x4){0.f,0.f,0.f,0.f};

  uint32_t asBase = (uint32_t)(uintptr_t)&As[0];
  uint32_t bsBase = (uint32_t)(uintptr_t)&Bs[0];
  const char* Ab = (const char*)A;
  const char* Wb = (const char*)W;

  for (int kt = 0; kt < 32; ++kt) {
    __syncthreads();
    #pragma unroll
    for (int issue = 0; issue < 2; ++issue) {
      int o = issue*4096 + t*16;
      int row  = o >> 6;
      int colb = o & 63;
      const char* ga = Ab + (size_t)(rowTile + row)*2048 + kt*64 + colb;
      const char* gb = Wb + (size_t)(colTile + row)*2048 + kt*64 + colb;
      uint32_t la = asBase + issue*4096 + (w<<10);
      uint32_t lb = bsBase + issue*4096 + (w<<10);
      __builtin_amdgcn_global_load_lds(
          (const AS1 void*)(uintptr_t)ga, (AS3 void*)(uintptr_t)la, 16, 0, 0);
      __builtin_amdgcn_global_load_lds(
          (const AS1 void*)(uintptr_t)gb, (AS3 void*)(uintptr_t)lb, 16, 0, 0);
    }
    __syncthreads();

    bf16x8 af[4], bfr[4];
    int krow = (lane >> 4) * 16;
    #pragma unroll
    for (int m=0;m<4;m++) {
      int r = wr*64 + m*16 + (lane&15);
      af[m] = *(const bf16x8*)((const char*)As + r*64 + krow);
    }
    #pragma unroll
    for (int n=0;n<4;n++) {
      int r = wc*64 + n*16 + (lane&15);
      bfr[n] = *(const bf16x8*)((const char*)Bs + r*64 + krow);
    }
    #pragma unroll
    for (int m=0;m<4;m++)
      #pragma unroll
      for (int n=0;n<4;n++)
        acc[m][n] = __builtin_amdgcn_mfma_f32_16x16x32_bf16(af[m], bfr[n], acc[m][n], 0,0,0);
  }

  // epilogue -> head-major [n*16+h][l][d]; A row = l*8+n, col = h*64+d
  #pragma unroll
  for (int n2=0;n2<4;n2++) {
    int gcol = colTile + wc*64 + n2*16 + (lane&15);
    int h = gcol >> 6, d = gcol & 63;
    float bv = bias[gcol]*bscale;
    #pragma unroll
    for (int m=0;m<4;m++) {
      int grow0 = rowTile + wr*64 + m*16 + ((lane>>4)<<2);
      #pragma unroll
      for (int r=0;r<4;r++) {
        int grow = grow0 + r;
        int l = grow >> 3, nn = grow & 7;
        C[((size_t)(nn*16 + h)*1024 + l)*64 + d] = f2bf(acc[m][n2][r] + bv);
      }
    }
  }
}

// ---------------------------------------------------------------------------
// Kernel 3: fused QK^T + attn_bias + softmax — wave-decoupled pipeline.
// Block = 16 q-rows x one batch-head, 4 waves, 48 KB LDS.
// Phase 1 has ZERO barriers: each wave stages its own 16 K-rows per chunk
// (wave-private 2 KB x2 dbuf via global_load_lds, involution-swizzled src),
// pipelined with counted s_waitcnt vmcnt(6). Bias enters as the MFMA C-seed
// (4 coalesced scalar f32 loads/lane/chunk, also in the vmcnt pipeline) so
// the 537 MB bias stream overlaps compute chunk-by-chunk (anti-convoy).
// Scores (bias included) -> f16 LDS (32 KB, row-XOR-swizzled).
// Phase 2 (after the single __syncthreads): wave-per-row softmax, pure
// coalesced f32x4 write stream (no global reads).
// ---------------------------------------------------------------------------
__global__ __launch_bounds__(256) void attn_softmax(
    const u16* __restrict__ Qh, const u16* __restrict__ Kh,
    const float* __restrict__ bias, float* __restrict__ out)
{
  __shared__ __align__(16) char scb[16*2048];      // 32 KB f16 scores, swizzled
  __shared__ __align__(16) char kbuf[2][4][2048];  // 16 KB: dbuf x wave x 16 rows
  const int t = threadIdx.x;
  const int lane = t & 63;
  const int w = t >> 6;
  const int ltile = blockIdx.x;     // 64 tiles of 16 q-rows
  const int b = blockIdx.y;         // 128 batch-heads
  const int q16 = lane & 15;
  const int sg  = lane >> 4;

  const char* Kb = (const char*)(Kh + (size_t)b*65536);
  const u16*  Qb = Qh + (size_t)b*65536 + (size_t)ltile*1024;   // 16 rows x 64

  // Q frags (A operand): q-row = q16, d = sg*8
  bf16x8 a0 = *(const bf16x8*)(Qb + q16*64 + sg*8);
  bf16x8 a1 = *(const bf16x8*)(Qb + q16*64 + sg*8 + 32);

  // Wave-private K staging: lane l covers LDS bytes l*16 of each 1 KB half.
  // LDS byte o (in 2KB wave buf): row = o>>7, col = o&127; stored swizzled:
  // src_global_col = col ^ ((row&7)<<4). Closed form per lane:
  const int stg_row = lane >> 3;                         // 0..7
  const int stg_off = (((lane & 7) ^ stg_row) << 4);     // pre-swizzled col
  const char* Kst = Kb + w*2048 + stg_row*128 + stg_off; // + g*8192 (+1024 for half 1)
  const uint32_t kw0 = (uint32_t)(uintptr_t)&kbuf[0][w][0];
  const uint32_t kw1 = (uint32_t)(uintptr_t)&kbuf[1][w][0];

  // Bias per-lane base: rows q = sg*4 + rr, col s = g*64 + w*16 + q16
  const float* bl = bias + ((size_t)b*1024 + ltile*16 + sg*4)*1024 + w*16 + q16;

  float bv[2][4];

  #define ISSUE_CHUNK(gg, dd) do {                                          \
    const char* s_ = Kst + (gg)*8192;                                       \
    uint32_t d_ = (dd) ? kw1 : kw0;                                         \
    __builtin_amdgcn_global_load_lds(                                       \
        (const AS1 void*)(uintptr_t)s_, (AS3 void*)(uintptr_t)d_, 16, 0, 0);\
    __builtin_amdgcn_global_load_lds(                                       \
        (const AS1 void*)(uintptr_t)(s_+1024),                              \
        (AS3 void*)(uintptr_t)(d_+1024), 16, 0, 0);                         \
    bv[dd][0] = bl[(gg)*64];                                                \
    bv[dd][1] = bl[(gg)*64 + 1024];                                         \
    bv[dd][2] = bl[(gg)*64 + 2048];                                         \
    bv[dd][3] = bl[(gg)*64 + 3072];                                         \
  } while(0)

  ISSUE_CHUNK(0, 0);   // prologue

  const int c0 = ((sg     ^ (q16 & 7)) << 4);
  const int c1 = (((4+sg) ^ (q16 & 7)) << 4);

  #pragma unroll
  for (int g = 0; g < 16; ++g) {
    const int d = g & 1;
    if (g < 15) ISSUE_CHUNK(g+1, d^1);
    if (g < 15) { asm volatile("s_waitcnt vmcnt(6)" ::: "memory"); }
    else        { asm volatile("s_waitcnt vmcnt(0)" ::: "memory"); }
    __builtin_amdgcn_sched_barrier(0);

    const char* kw = (const char*)&kbuf[d][w][0];
    bf16x8 b0 = *(const bf16x8*)(kw + q16*128 + c0);
    bf16x8 b1 = *(const bf16x8*)(kw + q16*128 + c1);
    f32x4 acc = { bv[d][0], bv[d][1], bv[d][2], bv[d][3] };
    acc = __builtin_amdgcn_mfma_f32_16x16x32_bf16(a0, b0, acc, 0,0,0);
    acc = __builtin_amdgcn_mfma_f32_16x16x32_bf16(a1, b1, acc, 0,0,0);

    const int scol = g*64 + w*16 + q16;
    #pragma unroll
    for (int rr=0; rr<4; ++rr) {
      int row = sg*4 + rr;
      int byte = (row*2048 + scol*2) ^ ((row&7)<<4);
      *(f16*)(scb + byte) = (f16)acc[rr];
    }
    __builtin_amdgcn_sched_barrier(0);  // pin: next issues after this compute
  }
  #undef ISSUE_CHUNK

  __syncthreads();

  // Phase 2: wave w owns rows {w, w+4, w+8, w+12}; scores already biased.
  #pragma unroll
  for (int rr=0;rr<4;rr++) {
    int row = rr*4 + w;
    int l_glob = ltile*16 + row;
    float* orow = out + ((size_t)b*1024 + l_glob)*1024;
    const int rswz = (row&7)<<4;
    float v[16];
    float mx = -1e30f;
    #pragma unroll
    for (int it=0; it<2; ++it) {
      int cb = it*1024 + lane*16;                 // logical byte offset in row
      f16x8 s8 = *(const f16x8*)(scb + ((row*2048 + cb) ^ rswz));
      #pragma unroll
      for (int j=0;j<8;j++) v[it*8+j] = (float)s8[j];
    }
    #pragma unroll
    for (int j=0;j<16;j++) mx = fmaxf(mx, v[j]);
    #pragma unroll
    for (int off=32; off>0; off>>=1) mx = fmaxf(mx, __shfl_xor(mx, off, 64));
    float sum = 0.f;
    #pragma unroll
    for (int j=0;j<16;j++) { v[j] = __expf(v[j]-mx); sum += v[j]; }
    #pragma unroll
    for (int off=32; off>0; off>>=1) sum += __shfl_xor(sum, off, 64);
    float inv = 1.0f / sum;
    #pragma unroll
    for (int it=0; it<2; ++it) {
      int col = it*512 + lane*8;
      f32x4 o4a = { v[it*8+0]*inv, v[it*8+1]*inv, v[it*8+2]*inv, v[it*8+3]*inv };
      f32x4 o4b = { v[it*8+4]*inv, v[it*8+5]*inv, v[it*8+6]*inv, v[it*8+7]*inv };
      *(f32x4*)(orow + col)     = o4a;
      *(f32x4*)(orow + col + 4) = o4b;
    }
  }
}

// ---------------------------------------------------------------------------
// Workspace layout (68 MB total):
//   qbf 16 MB | kbf 16 MB | wq 2 MB | wk 2 MB | Qh 16 MB | Kh 16 MB
// ---------------------------------------------------------------------------
extern "C" void kernel_launch(void* const* d_in, const int* in_sizes, int n_in,
                              void* d_out, int out_size, void* d_ws, size_t ws_size,
                              hipStream_t stream) {
  const float* query = (const float*)d_in[0];
  const float* key   = (const float*)d_in[1];
  const float* w     = (const float*)d_in[2];
  const float* bias  = (const float*)d_in[3];
  const float* abias = (const float*)d_in[4];
  float* out = (float*)d_out;

  char* ws = (char*)d_ws;
  const size_t QKB = (size_t)M_ROWS*E_DIM*2;  // 16 MB
  const size_t WB  = (size_t)E_DIM*E_DIM*2;   // 2 MB
  u16* qbf = (u16*)ws;  ws += QKB;
  u16* kbf = (u16*)ws;  ws += QKB;
  u16* wq  = (u16*)ws;  ws += WB;
  u16* wk  = (u16*)ws;  ws += WB;
  u16* Qh  = (u16*)ws;  ws += QKB;   // head-major [bh][l][d]
  u16* Kh  = (u16*)ws;  ws += QKB;   // head-major [bh][s][d]

  hipLaunchKernelGGL(convert_kernel, dim3(2048), dim3(256), 0, stream,
                     query, key, w, qbf, kbf, wq, wk);
  hipLaunchKernelGGL(proj_gemm, dim3(64, 8), dim3(256), 0, stream,
                     qbf, wq, bias, 0.125f, Qh);
  hipLaunchKernelGGL(proj_gemm, dim3(64, 8), dim3(256), 0, stream,
                     kbf, wk, bias + 1024, 1.0f, Kh);
  hipLaunchKernelGGL(attn_softmax, dim3(64, 128), dim3(256), 0, stream,
                     Qh, Kh, abias, out);
}

// Round 10
// 345.387 us; speedup vs baseline: 1.2132x; 1.0002x over previous
//
#include <hip/hip_runtime.h>
#include <hip/hip_bf16.h>
#include <stdint.h>

// Problem constants
#define L_DIM 1024
#define S_DIM 1024
#define N_DIM 8
#define E_DIM 1024
#define H_DIM 16
#define HD    64
#define BH    (N_DIM*H_DIM)    // 128 batch-heads
#define M_ROWS (L_DIM*N_DIM)   // 8192 rows for projection GEMMs

#define AS1 __attribute__((address_space(1)))
#define AS3 __attribute__((address_space(3)))

typedef __bf16 bf16x8 __attribute__((ext_vector_type(8)));
typedef float  f32x4  __attribute__((ext_vector_type(4)));
typedef _Float16 f16;
typedef _Float16 f16x8 __attribute__((ext_vector_type(8)));
typedef unsigned short u16;
typedef unsigned short u16x8 __attribute__((ext_vector_type(8)));

// round-to-nearest-even f32 -> bf16 (finite inputs only)
__device__ inline u16 f2bf(float x){
  unsigned int u = __float_as_uint(x);
  u = (u + 0x7FFFu + ((u >> 16) & 1u)) >> 16;
  return (u16)u;
}

// ---------------------------------------------------------------------------
// Kernel 0: convert query, key, Wq (x0.125 folded), Wk to bf16 (vectorized x8)
// ---------------------------------------------------------------------------
__global__ __launch_bounds__(256) void convert_kernel(
    const float* __restrict__ query, const float* __restrict__ key,
    const float* __restrict__ w,
    u16* __restrict__ qbf, u16* __restrict__ kbf,
    u16* __restrict__ wq, u16* __restrict__ wk)
{
  const int QN = M_ROWS*E_DIM;   // 8388608
  const int WN = E_DIM*E_DIM;    // 1048576
  const int total8 = (2*QN + 2*WN)/8;
  int stride = gridDim.x*blockDim.x;
  for (int g = blockIdx.x*blockDim.x + threadIdx.x; g < total8; g += stride) {
    int base = g*8;
    const float* src; u16* dst; float scale = 1.0f;
    if (base < QN)           { src = query + base;      dst = qbf + base; }
    else if (base < 2*QN)    { src = key + (base-QN);   dst = kbf + (base-QN); }
    else if (base < 2*QN+WN) { src = w + (base-2*QN);   dst = wq + (base-2*QN); scale = 0.125f; }
    else                     { src = w + (base-2*QN);   dst = wk + (base-2*QN-WN); }
    float4 v0 = *(const float4*)(src);
    float4 v1 = *(const float4*)(src+4);
    u16x8 o;
    o[0]=f2bf(v0.x*scale); o[1]=f2bf(v0.y*scale); o[2]=f2bf(v0.z*scale); o[3]=f2bf(v0.w*scale);
    o[4]=f2bf(v1.x*scale); o[5]=f2bf(v1.y*scale); o[6]=f2bf(v1.z*scale); o[7]=f2bf(v1.w*scale);
    *(u16x8*)dst = o;
  }
}

// ---------------------------------------------------------------------------
// Kernel 1/2: projection GEMM, C = A @ W^T + bscale*bias, bf16 in, f32 acc.
// Output HEAD-MAJOR: C[(n*16+h)][l_or_s][d] -> contiguous 128 KB per head.
// (R3-proven form: two sequential launches.)
// ---------------------------------------------------------------------------
__global__ __launch_bounds__(256) void proj_gemm(
    const u16* __restrict__ A, const u16* __restrict__ W,
    const float* __restrict__ bias, float bscale,
    u16* __restrict__ C)
{
  __shared__ __align__(16) u16 As[128*32];
  __shared__ __align__(16) u16 Bs[128*32];
  const int t = threadIdx.x;
  const int lane = t & 63;
  const int w = t >> 6;
  const int wr = w >> 1, wc = w & 1;
  const int rowTile = blockIdx.x * 128;
  const int colTile = blockIdx.y * 128;

  f32x4 acc[4][4];
  #pragma unroll
  for (int m=0;m<4;m++)
    #pragma unroll
    for (int n=0;n<4;n++) acc[m][n] = (f32x4){0.f,0.f,0.f,0.f};

  uint32_t asBase = (uint32_t)(uintptr_t)&As[0];
  uint32_t bsBase = (uint32_t)(uintptr_t)&Bs[0];
  const char* Ab = (const char*)A;
  const char* Wb = (const char*)W;

  for (int kt = 0; kt < 32; ++kt) {
    __syncthreads();
    #pragma unroll
    for (int issue = 0; issue < 2; ++issue) {
      int o = issue*4096 + t*16;
      int row  = o >> 6;
      int colb = o & 63;
      const char* ga = Ab + (size_t)(rowTile + row)*2048 + kt*64 + colb;
      const char* gb = Wb + (size_t)(colTile + row)*2048 + kt*64 + colb;
      uint32_t la = asBase + issue*4096 + (w<<10);
      uint32_t lb = bsBase + issue*4096 + (w<<10);
      __builtin_amdgcn_global_load_lds(
          (const AS1 void*)(uintptr_t)ga, (AS3 void*)(uintptr_t)la, 16, 0, 0);
      __builtin_amdgcn_global_load_lds(
          (const AS1 void*)(uintptr_t)gb, (AS3 void*)(uintptr_t)lb, 16, 0, 0);
    }
    __syncthreads();

    bf16x8 af[4], bfr[4];
    int krow = (lane >> 4) * 16;
    #pragma unroll
    for (int m=0;m<4;m++) {
      int r = wr*64 + m*16 + (lane&15);
      af[m] = *(const bf16x8*)((const char*)As + r*64 + krow);
    }
    #pragma unroll
    for (int n=0;n<4;n++) {
      int r = wc*64 + n*16 + (lane&15);
      bfr[n] = *(const bf16x8*)((const char*)Bs + r*64 + krow);
    }
    #pragma unroll
    for (int m=0;m<4;m++)
      #pragma unroll
      for (int n=0;n<4;n++)
        acc[m][n] = __builtin_amdgcn_mfma_f32_16x16x32_bf16(af[m], bfr[n], acc[m][n], 0,0,0);
  }

  // epilogue -> head-major [n*16+h][l][d]; A row = l*8+n, col = h*64+d
  #pragma unroll
  for (int n2=0;n2<4;n2++) {
    int gcol = colTile + wc*64 + n2*16 + (lane&15);
    int h = gcol >> 6, d = gcol & 63;
    float bv = bias[gcol]*bscale;
    #pragma unroll
    for (int m=0;m<4;m++) {
      int grow0 = rowTile + wr*64 + m*16 + ((lane>>4)<<2);
      #pragma unroll
      for (int r=0;r<4;r++) {
        int grow = grow0 + r;
        int l = grow >> 3, nn = grow & 7;
        C[((size_t)(nn*16 + h)*1024 + l)*64 + d] = f2bf(acc[m][n2][r] + bv);
      }
    }
  }
}

// ---------------------------------------------------------------------------
// Kernel 3: fused QK^T + attn_bias + softmax — wave-decoupled pipeline.
// Block = 16 q-rows x one batch-head, 4 waves, 48 KB LDS.
// Phase 1 has ZERO barriers: each wave stages its own 16 K-rows per chunk
// (wave-private 2 KB x2 dbuf via global_load_lds, involution-swizzled src),
// pipelined with counted s_waitcnt vmcnt(6). Bias enters as the MFMA C-seed
// (4 coalesced scalar f32 loads/lane/chunk, also in the vmcnt pipeline) so
// the 537 MB bias stream overlaps compute chunk-by-chunk (anti-convoy).
// Scores (bias included) -> f16 LDS (32 KB, row-XOR-swizzled).
// Phase 2 (after the single __syncthreads): wave-per-row softmax, pure
// coalesced f32x4 write stream (no global reads).
// ---------------------------------------------------------------------------
__global__ __launch_bounds__(256) void attn_softmax(
    const u16* __restrict__ Qh, const u16* __restrict__ Kh,
    const float* __restrict__ bias, float* __restrict__ out)
{
  __shared__ __align__(16) char scb[16*2048];      // 32 KB f16 scores, swizzled
  __shared__ __align__(16) char kbuf[2][4][2048];  // 16 KB: dbuf x wave x 16 rows
  const int t = threadIdx.x;
  const int lane = t & 63;
  const int w = t >> 6;
  const int ltile = blockIdx.x;     // 64 tiles of 16 q-rows
  const int b = blockIdx.y;         // 128 batch-heads
  const int q16 = lane & 15;
  const int sg  = lane >> 4;

  const char* Kb = (const char*)(Kh + (size_t)b*65536);
  const u16*  Qb = Qh + (size_t)b*65536 + (size_t)ltile*1024;   // 16 rows x 64

  // Q frags (A operand): q-row = q16, d = sg*8
  bf16x8 a0 = *(const bf16x8*)(Qb + q16*64 + sg*8);
  bf16x8 a1 = *(const bf16x8*)(Qb + q16*64 + sg*8 + 32);

  // Wave-private K staging: lane l covers LDS bytes l*16 of each 1 KB half.
  // LDS byte o (in 2KB wave buf): row = o>>7, col = o&127; stored swizzled:
  // src_global_col = col ^ ((row&7)<<4). Closed form per lane:
  const int stg_row = lane >> 3;                         // 0..7
  const int stg_off = (((lane & 7) ^ stg_row) << 4);     // pre-swizzled col
  const char* Kst = Kb + w*2048 + stg_row*128 + stg_off; // + g*8192 (+1024 for half 1)
  const uint32_t kw0 = (uint32_t)(uintptr_t)&kbuf[0][w][0];
  const uint32_t kw1 = (uint32_t)(uintptr_t)&kbuf[1][w][0];

  // Bias per-lane base: rows q = sg*4 + rr, col s = g*64 + w*16 + q16
  const float* bl = bias + ((size_t)b*1024 + ltile*16 + sg*4)*1024 + w*16 + q16;

  float bv[2][4];

  #define ISSUE_CHUNK(gg, dd) do {                                          \
    const char* s_ = Kst + (gg)*8192;                                       \
    uint32_t d_ = (dd) ? kw1 : kw0;                                         \
    __builtin_amdgcn_global_load_lds(                                       \
        (const AS1 void*)(uintptr_t)s_, (AS3 void*)(uintptr_t)d_, 16, 0, 0);\
    __builtin_amdgcn_global_load_lds(                                       \
        (const AS1 void*)(uintptr_t)(s_+1024),                              \
        (AS3 void*)(uintptr_t)(d_+1024), 16, 0, 0);                         \
    bv[dd][0] = bl[(gg)*64];                                                \
    bv[dd][1] = bl[(gg)*64 + 1024];                                         \
    bv[dd][2] = bl[(gg)*64 + 2048];                                         \
    bv[dd][3] = bl[(gg)*64 + 3072];                                         \
  } while(0)

  ISSUE_CHUNK(0, 0);   // prologue

  const int c0 = ((sg     ^ (q16 & 7)) << 4);
  const int c1 = (((4+sg) ^ (q16 & 7)) << 4);

  #pragma unroll
  for (int g = 0; g < 16; ++g) {
    const int d = g & 1;
    if (g < 15) ISSUE_CHUNK(g+1, d^1);
    if (g < 15) { asm volatile("s_waitcnt vmcnt(6)" ::: "memory"); }
    else        { asm volatile("s_waitcnt vmcnt(0)" ::: "memory"); }
    __builtin_amdgcn_sched_barrier(0);

    const char* kw = (const char*)&kbuf[d][w][0];
    bf16x8 b0 = *(const bf16x8*)(kw + q16*128 + c0);
    bf16x8 b1 = *(const bf16x8*)(kw + q16*128 + c1);
    f32x4 acc = { bv[d][0], bv[d][1], bv[d][2], bv[d][3] };
    acc = __builtin_amdgcn_mfma_f32_16x16x32_bf16(a0, b0, acc, 0,0,0);
    acc = __builtin_amdgcn_mfma_f32_16x16x32_bf16(a1, b1, acc, 0,0,0);

    const int scol = g*64 + w*16 + q16;
    #pragma unroll
    for (int rr=0; rr<4; ++rr) {
      int row = sg*4 + rr;
      int byte = (row*2048 + scol*2) ^ ((row&7)<<4);
      *(f16*)(scb + byte) = (f16)acc[rr];
    }
    __builtin_amdgcn_sched_barrier(0);  // pin: next issues after this compute
  }
  #undef ISSUE_CHUNK

  __syncthreads();

  // Phase 2: wave w owns rows {w, w+4, w+8, w+12}; scores already biased.
  #pragma unroll
  for (int rr=0;rr<4;rr++) {
    int row = rr*4 + w;
    int l_glob = ltile*16 + row;
    float* orow = out + ((size_t)b*1024 + l_glob)*1024;
    const int rswz = (row&7)<<4;
    float v[16];
    float mx = -1e30f;
    #pragma unroll
    for (int it=0; it<2; ++it) {
      int cb = it*1024 + lane*16;                 // logical byte offset in row
      f16x8 s8 = *(const f16x8*)(scb + ((row*2048 + cb) ^ rswz));
      #pragma unroll
      for (int j=0;j<8;j++) v[it*8+j] = (float)s8[j];
    }
    #pragma unroll
    for (int j=0;j<16;j++) mx = fmaxf(mx, v[j]);
    #pragma unroll
    for (int off=32; off>0; off>>=1) mx = fmaxf(mx, __shfl_xor(mx, off, 64));
    float sum = 0.f;
    #pragma unroll
    for (int j=0;j<16;j++) { v[j] = __expf(v[j]-mx); sum += v[j]; }
    #pragma unroll
    for (int off=32; off>0; off>>=1) sum += __shfl_xor(sum, off, 64);
    float inv = 1.0f / sum;
    #pragma unroll
    for (int it=0; it<2; ++it) {
      int col = it*512 + lane*8;
      f32x4 o4a = { v[it*8+0]*inv, v[it*8+1]*inv, v[it*8+2]*inv, v[it*8+3]*inv };
      f32x4 o4b = { v[it*8+4]*inv, v[it*8+5]*inv, v[it*8+6]*inv, v[it*8+7]*inv };
      *(f32x4*)(orow + col)     = o4a;
      *(f32x4*)(orow + col + 4) = o4b;
    }
  }
}

// ---------------------------------------------------------------------------
// Workspace layout (68 MB total):
//   qbf 16 MB | kbf 16 MB | wq 2 MB | wk 2 MB | Qh 16 MB | Kh 16 MB
// ---------------------------------------------------------------------------
extern "C" void kernel_launch(void* const* d_in, const int* in_sizes, int n_in,
                              void* d_out, int out_size, void* d_ws, size_t ws_size,
                              hipStream_t stream) {
  const float* query = (const float*)d_in[0];
  const float* key   = (const float*)d_in[1];
  const float* w     = (const float*)d_in[2];
  const float* bias  = (const float*)d_in[3];
  const float* abias = (const float*)d_in[4];
  float* out = (float*)d_out;

  char* ws = (char*)d_ws;
  const size_t QKB = (size_t)M_ROWS*E_DIM*2;  // 16 MB
  const size_t WB  = (size_t)E_DIM*E_DIM*2;   // 2 MB
  u16* qbf = (u16*)ws;  ws += QKB;
  u16* kbf = (u16*)ws;  ws += QKB;
  u16* wq  = (u16*)ws;  ws += WB;
  u16* wk  = (u16*)ws;  ws += WB;
  u16* Qh  = (u16*)ws;  ws += QKB;   // head-major [bh][l][d]
  u16* Kh  = (u16*)ws;  ws += QKB;   // head-major [bh][s][d]

  hipLaunchKernelGGL(convert_kernel, dim3(2048), dim3(256), 0, stream,
                     query, key, w, qbf, kbf, wq, wk);
  hipLaunchKernelGGL(proj_gemm, dim3(64, 8), dim3(256), 0, stream,
                     qbf, wq, bias, 0.125f, Qh);
  hipLaunchKernelGGL(proj_gemm, dim3(64, 8), dim3(256), 0, stream,
                     kbf, wk, bias + 1024, 1.0f, Kh);
  hipLaunchKernelGGL(attn_softmax, dim3(64, 128), dim3(256), 0, stream,
                     Qh, Kh, abias, out);
}

// Round 12
// 335.599 us; speedup vs baseline: 1.2486x; 1.0292x over previous
//
#include <hip/hip_runtime.h>
#include <hip/hip_bf16.h>
#include <stdint.h>

// Problem constants
#define L_DIM 1024
#define S_DIM 1024
#define N_DIM 8
#define E_DIM 1024
#define H_DIM 16
#define HD    64
#define BH    (N_DIM*H_DIM)    // 128 batch-heads
#define M_ROWS (L_DIM*N_DIM)   // 8192 rows for projection GEMMs

#define AS1 __attribute__((address_space(1)))
#define AS3 __attribute__((address_space(3)))

typedef __bf16 bf16x8 __attribute__((ext_vector_type(8)));
typedef float  f32x4  __attribute__((ext_vector_type(4)));
typedef float  f32x8  __attribute__((ext_vector_type(8)));
typedef _Float16 f16;
typedef _Float16 f16x8 __attribute__((ext_vector_type(8)));
typedef unsigned short u16;
typedef unsigned short u16x8 __attribute__((ext_vector_type(8)));

// round-to-nearest-even f32 -> bf16 (finite inputs only)
__device__ inline u16 f2bf(float x){
  unsigned int u = __float_as_uint(x);
  u = (u + 0x7FFFu + ((u >> 16) & 1u)) >> 16;
  return (u16)u;
}

// ---------------------------------------------------------------------------
// Kernel 0: convert W only -> wq (x0.125 folded), wk.
// R11 BUG FIX: the wk branch must read w + base (rows E..2E of in_proj_weight,
// the K weight), NOT w + (base-WN) which re-reads the Q weight.
// ---------------------------------------------------------------------------
__global__ __launch_bounds__(256) void convert_w(
    const float* __restrict__ w,
    u16* __restrict__ wq, u16* __restrict__ wk)
{
  const int WN = E_DIM*E_DIM;    // 1048576
  int g = blockIdx.x*blockDim.x + threadIdx.x;   // grid exactly 2*WN/8 threads
  int base = g*8;
  const float* src; u16* dst; float scale;
  if (base < WN) { src = w + base; dst = wq + base;      scale = 0.125f; }
  else           { src = w + base; dst = wk + (base-WN); scale = 1.0f;   }
  float4 v0 = *(const float4*)(src);
  float4 v1 = *(const float4*)(src+4);
  u16x8 o;
  o[0]=f2bf(v0.x*scale); o[1]=f2bf(v0.y*scale); o[2]=f2bf(v0.z*scale); o[3]=f2bf(v0.w*scale);
  o[4]=f2bf(v1.x*scale); o[5]=f2bf(v1.y*scale); o[6]=f2bf(v1.z*scale); o[7]=f2bf(v1.w*scale);
  *(u16x8*)dst = o;
}

// ---------------------------------------------------------------------------
// Kernel 1/2: projection GEMM with FUSED f32->bf16 conversion of A.
// C = (bf16(A) @ W^T) + bscale*bias; A is the raw f32 query/key tensor
// ([8192][1024], row = l*8+n). A staged as f32 through 16 KB LDS via
// global_load_lds with involution-XOR-swizzled SOURCE (rule #21): LDS byte
// o (128 B rows): src col = (o&127) ^ ((row&7)<<4). A-frag ds_read applies
// the same XOR -> conflict-benign. Frags converted in-register.
// B (pre-converted W) staged bf16 linear. Output HEAD-MAJOR
// C[(n*16+h)][l_or_s][d] -> contiguous 128 KB per head.
// ---------------------------------------------------------------------------
__global__ __launch_bounds__(256) void proj_gemm(
    const float* __restrict__ A, const u16* __restrict__ W,
    const float* __restrict__ bias, float bscale,
    u16* __restrict__ C)
{
  __shared__ __align__(16) float Asf[128*32];   // 16 KB f32, swizzled rows
  __shared__ __align__(16) u16  Bs[128*32];     //  8 KB bf16, linear
  const int t = threadIdx.x;
  const int lane = t & 63;
  const int w = t >> 6;
  const int wr = w >> 1, wc = w & 1;
  const int rowTile = blockIdx.x * 128;
  const int colTile = blockIdx.y * 128;
  const int q16 = lane & 15;
  const int sg  = lane >> 4;

  f32x4 acc[4][4];
  #pragma unroll
  for (int m=0;m<4;m++)
    #pragma unroll
    for (int n=0;n<4;n++) acc[m][n] = (f32x4){0.f,0.f,0.f,0.f};

  uint32_t asBase = (uint32_t)(uintptr_t)&Asf[0];
  uint32_t bsBase = (uint32_t)(uintptr_t)&Bs[0];
  const char* Ab = (const char*)A;   // row stride 4096 B
  const char* Wb = (const char*)W;   // row stride 2048 B

  for (int kt = 0; kt < 32; ++kt) {
    __syncthreads();
    // ---- A: 16 KB f32, 4 issues of 4 KB; source pre-swizzled (involution)
    #pragma unroll
    for (int issue = 0; issue < 4; ++issue) {
      int o = issue*4096 + t*16;
      int row  = o >> 7;                       // 128 B per row (32 f32)
      int colb = o & 127;
      int scol = colb ^ ((row&7)<<4);
      const char* ga = Ab + (size_t)(rowTile + row)*4096 + kt*128 + scol;
      uint32_t la = asBase + issue*4096 + (w<<10);
      __builtin_amdgcn_global_load_lds(
          (const AS1 void*)(uintptr_t)ga, (AS3 void*)(uintptr_t)la, 16, 0, 0);
    }
    // ---- B: 8 KB bf16, 2 issues of 4 KB, linear (as in R3)
    #pragma unroll
    for (int issue = 0; issue < 2; ++issue) {
      int o = issue*4096 + t*16;
      int row  = o >> 6;                       // 64 B per row (32 bf16)
      int colb = o & 63;
      const char* gb = Wb + (size_t)(colTile + row)*2048 + kt*64 + colb;
      uint32_t lb = bsBase + issue*4096 + (w<<10);
      __builtin_amdgcn_global_load_lds(
          (const AS1 void*)(uintptr_t)gb, (AS3 void*)(uintptr_t)lb, 16, 0, 0);
    }
    __syncthreads();

    bf16x8 af[4], bfr[4];
    #pragma unroll
    for (int m=0;m<4;m++) {
      int r = wr*64 + m*16 + q16;
      int swk = (r&7)<<4;
      const char* rb = (const char*)Asf + r*128;
      f32x4 lo = *(const f32x4*)(rb + ((sg*32   ) ^ swk));
      f32x4 hi = *(const f32x4*)(rb + ((sg*32+16) ^ swk));
      f32x8 a8 = __builtin_shufflevector(lo, hi, 0,1,2,3,4,5,6,7);
      af[m] = __builtin_convertvector(a8, bf16x8);
    }
    #pragma unroll
    for (int n=0;n<4;n++) {
      int r = wc*64 + n*16 + q16;
      bfr[n] = *(const bf16x8*)((const char*)Bs + r*64 + sg*16);
    }
    #pragma unroll
    for (int m=0;m<4;m++)
      #pragma unroll
      for (int n=0;n<4;n++)
        acc[m][n] = __builtin_amdgcn_mfma_f32_16x16x32_bf16(af[m], bfr[n], acc[m][n], 0,0,0);
  }

  // epilogue -> head-major [n*16+h][l][d]; A row = l*8+n, col = h*64+d
  #pragma unroll
  for (int n2=0;n2<4;n2++) {
    int gcol = colTile + wc*64 + n2*16 + q16;
    int h = gcol >> 6, d = gcol & 63;
    float bv = bias[gcol]*bscale;
    #pragma unroll
    for (int m=0;m<4;m++) {
      int grow0 = rowTile + wr*64 + m*16 + (sg<<2);
      #pragma unroll
      for (int r=0;r<4;r++) {
        int grow = grow0 + r;
        int l = grow >> 3, nn = grow & 7;
        C[((size_t)(nn*16 + h)*1024 + l)*64 + d] = f2bf(acc[m][n2][r] + bv);
      }
    }
  }
}

// ---------------------------------------------------------------------------
// Kernel 3: fused QK^T + attn_bias + softmax — EXACT R3 form (best measured).
// Block = (16 q-rows) x (one batch-head), 4 waves, 40 KB LDS.
// Phase 1: K staged through 8 KB LDS chunks via coalesced global_load_lds
//   (linear dest + involution-swizzled source); fragment ds_reads apply the
//   same swizzle -> 2-way (free) bank access. Wave w computes s-tile g*4+w
//   per chunk (2 MFMA over hd=64), scores -> f16 LDS (32 KB, row-swizzled).
// Phase 2: wave-per-row softmax, PLAIN coalesced f32x4 bias read + out write.
// ---------------------------------------------------------------------------
__global__ __launch_bounds__(256) void attn_softmax(
    const u16* __restrict__ Qh, const u16* __restrict__ Kh,
    const float* __restrict__ bias, float* __restrict__ out)
{
  __shared__ __align__(16) char scb[16*2048];    // 32 KB f16 scores, swizzled
  __shared__ __align__(16) char kbuf[8192];      // 64 s-rows x 64 d, swizzled
  const int t = threadIdx.x;
  const int lane = t & 63;
  const int w = t >> 6;
  const int ltile = blockIdx.x;     // 64 tiles of 16 q-rows
  const int b = blockIdx.y;         // 128 batch-heads

  const char* Kb = (const char*)(Kh + (size_t)b*1024*64);               // 128 KB
  const u16*  Qb = Qh + (size_t)b*1024*64 + (size_t)ltile*16*64;        // 2 KB

  // A-frags: q-row = lane&15 (row stride 128 B), d = (lane>>4)*8
  int qoff = (lane&15)*64 + (lane>>4)*8;
  bf16x8 a0 = *(const bf16x8*)(Qb + qoff);
  bf16x8 a1 = *(const bf16x8*)(Qb + qoff + 32);

  const int rowBase = (lane>>4)*4;
  uint32_t kbase = (uint32_t)(uintptr_t)&kbuf[0];

  for (int g = 0; g < 16; ++g) {
    __syncthreads();   // previous chunk's readers done before overwrite
    #pragma unroll
    for (int rd = 0; rd < 2; ++rd) {
      int o = rd*4096 + t*16;                    // linear LDS byte offset
      int src = o ^ (((o>>7)&7)<<4);             // inverse swizzle (involution)
      __builtin_amdgcn_global_load_lds(
          (const AS1 void*)(uintptr_t)(Kb + (size_t)g*8192 + src),
          (AS3 void*)(uintptr_t)(kbase + rd*4096 + (w<<10)), 16, 0, 0);
    }
    __syncthreads();   // staging visible (compiler drains vmcnt before barrier)

    // wave w: s-tile st = g*4+w, local rows r = w*16 + (lane&15)
    int r = w*16 + (lane&15);
    int byte0 = r*128 + ((lane>>4)*16);
    int swzk = (r&7)<<4;
    bf16x8 b0 = *(const bf16x8*)(kbuf + ((byte0      ) ^ swzk));
    bf16x8 b1 = *(const bf16x8*)(kbuf + ((byte0 + 64 ) ^ swzk));
    f32x4 acc = {0.f,0.f,0.f,0.f};
    acc = __builtin_amdgcn_mfma_f32_16x16x32_bf16(a0, b0, acc, 0,0,0);
    acc = __builtin_amdgcn_mfma_f32_16x16x32_bf16(a1, b1, acc, 0,0,0);

    int scol = g*64 + w*16 + (lane & 15);        // global s index
    #pragma unroll
    for (int rr=0;rr<4;rr++) {
      int row = rowBase + rr;
      int byte = (row*2048 + scol*2) ^ ((row&7)<<4);
      *(f16*)(scb + byte) = (f16)acc[rr];
    }
  }
  __syncthreads();

  #pragma unroll
  for (int rr=0;rr<4;rr++) {
    int row = rr*4 + w;                       // wave w owns rows {w, w+4, w+8, w+12}
    int l_glob = ltile*16 + row;
    const float* brow = bias + ((size_t)b*1024 + l_glob)*1024;
    float*       orow = out  + ((size_t)b*1024 + l_glob)*1024;
    const int swz = (row&7)<<4;
    float v[16];
    float mx = -1e30f;
    #pragma unroll
    for (int it=0; it<2; ++it) {
      int cb = it*1024 + lane*16;                 // logical byte offset in row
      f16x8 s8 = *(const f16x8*)(scb + ((row*2048 + cb) ^ swz));
      int col = it*512 + lane*8;
      f32x4 b4a = *(const f32x4*)(brow + col);
      f32x4 b4b = *(const f32x4*)(brow + col + 4);
      #pragma unroll
      for (int j=0;j<4;j++) v[it*8+j]   = (float)s8[j]   + b4a[j];
      #pragma unroll
      for (int j=0;j<4;j++) v[it*8+4+j] = (float)s8[4+j] + b4b[j];
    }
    #pragma unroll
    for (int j=0;j<16;j++) mx = fmaxf(mx, v[j]);
    #pragma unroll
    for (int off=32; off>0; off>>=1) mx = fmaxf(mx, __shfl_xor(mx, off, 64));
    float sum = 0.f;
    #pragma unroll
    for (int j=0;j<16;j++) { v[j] = __expf(v[j]-mx); sum += v[j]; }
    #pragma unroll
    for (int off=32; off>0; off>>=1) sum += __shfl_xor(sum, off, 64);
    float inv = 1.0f / sum;
    #pragma unroll
    for (int it=0; it<2; ++it) {
      int col = it*512 + lane*8;
      f32x4 o4a = { v[it*8+0]*inv, v[it*8+1]*inv, v[it*8+2]*inv, v[it*8+3]*inv };
      f32x4 o4b = { v[it*8+4]*inv, v[it*8+5]*inv, v[it*8+6]*inv, v[it*8+7]*inv };
      *(f32x4*)(orow + col)     = o4a;
      *(f32x4*)(orow + col + 4) = o4b;
    }
  }
}

// ---------------------------------------------------------------------------
// Workspace layout (36 MB total):
//   wq 2 MB | wk 2 MB | Qh 16 MB | Kh 16 MB
// ---------------------------------------------------------------------------
extern "C" void kernel_launch(void* const* d_in, const int* in_sizes, int n_in,
                              void* d_out, int out_size, void* d_ws, size_t ws_size,
                              hipStream_t stream) {
  const float* query = (const float*)d_in[0];
  const float* key   = (const float*)d_in[1];
  const float* w     = (const float*)d_in[2];
  const float* bias  = (const float*)d_in[3];
  const float* abias = (const float*)d_in[4];
  float* out = (float*)d_out;

  char* ws = (char*)d_ws;
  const size_t QKB = (size_t)M_ROWS*E_DIM*2;  // 16 MB
  const size_t WB  = (size_t)E_DIM*E_DIM*2;   // 2 MB
  u16* wq  = (u16*)ws;  ws += WB;
  u16* wk  = (u16*)ws;  ws += WB;
  u16* Qh  = (u16*)ws;  ws += QKB;   // head-major [bh][l][d]
  u16* Kh  = (u16*)ws;  ws += QKB;   // head-major [bh][s][d]

  hipLaunchKernelGGL(convert_w, dim3(2*E_DIM*E_DIM/8/256), dim3(256), 0, stream,
                     w, wq, wk);
  hipLaunchKernelGGL(proj_gemm, dim3(64, 8), dim3(256), 0, stream,
                     query, wq, bias, 0.125f, Qh);
  hipLaunchKernelGGL(proj_gemm, dim3(64, 8), dim3(256), 0, stream,
                     key, wk, bias + 1024, 1.0f, Kh);
  hipLaunchKernelGGL(attn_softmax, dim3(64, 128), dim3(256), 0, stream,
                     Qh, Kh, abias, out);
}

// Round 13
// 332.024 us; speedup vs baseline: 1.2621x; 1.0108x over previous
//
#include <hip/hip_runtime.h>
#include <hip/hip_bf16.h>
#include <stdint.h>

// Problem constants
#define L_DIM 1024
#define S_DIM 1024
#define N_DIM 8
#define E_DIM 1024
#define H_DIM 16
#define HD    64
#define BH    (N_DIM*H_DIM)    // 128 batch-heads
#define M_ROWS (L_DIM*N_DIM)   // 8192 rows for projection GEMMs

#define AS1 __attribute__((address_space(1)))
#define AS3 __attribute__((address_space(3)))

typedef __bf16 bf16x8 __attribute__((ext_vector_type(8)));
typedef float  f32x4  __attribute__((ext_vector_type(4)));
typedef _Float16 f16;
typedef _Float16 f16x8 __attribute__((ext_vector_type(8)));
typedef unsigned short u16;
typedef unsigned short u16x8 __attribute__((ext_vector_type(8)));

// round-to-nearest-even f32 -> bf16 (finite inputs only)
__device__ inline u16 f2bf(float x){
  unsigned int u = __float_as_uint(x);
  u = (u + 0x7FFFu + ((u >> 16) & 1u)) >> 16;
  return (u16)u;
}

// ---------------------------------------------------------------------------
// Kernel 0: convert query, key, Wq (x0.125 folded), Wk to bf16 (vectorized x8)
// (R3-proven form)
// ---------------------------------------------------------------------------
__global__ __launch_bounds__(256) void convert_kernel(
    const float* __restrict__ query, const float* __restrict__ key,
    const float* __restrict__ w,
    u16* __restrict__ qbf, u16* __restrict__ kbf,
    u16* __restrict__ wq, u16* __restrict__ wk)
{
  const int QN = M_ROWS*E_DIM;   // 8388608
  const int WN = E_DIM*E_DIM;    // 1048576
  const int total8 = (2*QN + 2*WN)/8;
  int stride = gridDim.x*blockDim.x;
  for (int g = blockIdx.x*blockDim.x + threadIdx.x; g < total8; g += stride) {
    int base = g*8;
    const float* src; u16* dst; float scale = 1.0f;
    if (base < QN)           { src = query + base;      dst = qbf + base; }
    else if (base < 2*QN)    { src = key + (base-QN);   dst = kbf + (base-QN); }
    else if (base < 2*QN+WN) { src = w + (base-2*QN);   dst = wq + (base-2*QN); scale = 0.125f; }
    else                     { src = w + (base-2*QN);   dst = wk + (base-2*QN-WN); }
    float4 v0 = *(const float4*)(src);
    float4 v1 = *(const float4*)(src+4);
    u16x8 o;
    o[0]=f2bf(v0.x*scale); o[1]=f2bf(v0.y*scale); o[2]=f2bf(v0.z*scale); o[3]=f2bf(v0.w*scale);
    o[4]=f2bf(v1.x*scale); o[5]=f2bf(v1.y*scale); o[6]=f2bf(v1.z*scale); o[7]=f2bf(v1.w*scale);
    *(u16x8*)dst = o;
  }
}

// ---------------------------------------------------------------------------
// Kernel 1/2: projection GEMM, C = A @ W^T + bscale*bias, bf16 in, f32 acc.
// Output HEAD-MAJOR: C[(n*16+h)][l_or_s][d] -> contiguous 128 KB per head.
// (R3-proven form)
// ---------------------------------------------------------------------------
__global__ __launch_bounds__(256) void proj_gemm(
    const u16* __restrict__ A, const u16* __restrict__ W,
    const float* __restrict__ bias, float bscale,
    u16* __restrict__ C)
{
  __shared__ __align__(16) u16 As[128*32];
  __shared__ __align__(16) u16 Bs[128*32];
  const int t = threadIdx.x;
  const int lane = t & 63;
  const int w = t >> 6;
  const int wr = w >> 1, wc = w & 1;
  const int rowTile = blockIdx.x * 128;
  const int colTile = blockIdx.y * 128;

  f32x4 acc[4][4];
  #pragma unroll
  for (int m=0;m<4;m++)
    #pragma unroll
    for (int n=0;n<4;n++) acc[m][n] = (f32x4){0.f,0.f,0.f,0.f};

  uint32_t asBase = (uint32_t)(uintptr_t)&As[0];
  uint32_t bsBase = (uint32_t)(uintptr_t)&Bs[0];
  const char* Ab = (const char*)A;
  const char* Wb = (const char*)W;

  for (int kt = 0; kt < 32; ++kt) {
    __syncthreads();
    #pragma unroll
    for (int issue = 0; issue < 2; ++issue) {
      int o = issue*4096 + t*16;
      int row  = o >> 6;
      int colb = o & 63;
      const char* ga = Ab + (size_t)(rowTile + row)*2048 + kt*64 + colb;
      const char* gb = Wb + (size_t)(colTile + row)*2048 + kt*64 + colb;
      uint32_t la = asBase + issue*4096 + (w<<10);
      uint32_t lb = bsBase + issue*4096 + (w<<10);
      __builtin_amdgcn_global_load_lds(
          (const AS1 void*)(uintptr_t)ga, (AS3 void*)(uintptr_t)la, 16, 0, 0);
      __builtin_amdgcn_global_load_lds(
          (const AS1 void*)(uintptr_t)gb, (AS3 void*)(uintptr_t)lb, 16, 0, 0);
    }
    __syncthreads();

    bf16x8 af[4], bfr[4];
    int krow = (lane >> 4) * 16;
    #pragma unroll
    for (int m=0;m<4;m++) {
      int r = wr*64 + m*16 + (lane&15);
      af[m] = *(const bf16x8*)((const char*)As + r*64 + krow);
    }
    #pragma unroll
    for (int n=0;n<4;n++) {
      int r = wc*64 + n*16 + (lane&15);
      bfr[n] = *(const bf16x8*)((const char*)Bs + r*64 + krow);
    }
    #pragma unroll
    for (int m=0;m<4;m++)
      #pragma unroll
      for (int n=0;n<4;n++)
        acc[m][n] = __builtin_amdgcn_mfma_f32_16x16x32_bf16(af[m], bfr[n], acc[m][n], 0,0,0);
  }

  // epilogue -> head-major [n*16+h][l][d]; A row = l*8+n, col = h*64+d
  #pragma unroll
  for (int n2=0;n2<4;n2++) {
    int gcol = colTile + wc*64 + n2*16 + (lane&15);
    int h = gcol >> 6, d = gcol & 63;
    float bv = bias[gcol]*bscale;
    #pragma unroll
    for (int m=0;m<4;m++) {
      int grow0 = rowTile + wr*64 + m*16 + ((lane>>4)<<2);
      #pragma unroll
      for (int r=0;r<4;r++) {
        int grow = grow0 + r;
        int l = grow >> 3, nn = grow & 7;
        C[((size_t)(nn*16 + h)*1024 + l)*64 + d] = f2bf(acc[m][n2][r] + bv);
      }
    }
  }
}

// ---------------------------------------------------------------------------
// Kernel 3: fused QK^T + attn_bias + softmax — R3 structure widened to
// 32 q-rows / 8 waves per block (halves K re-read amplification + barriers
// per output; occupancy unchanged: 72 KB -> 2 blocks/CU x 16 waves = same
// 16 waves/CU as R3's 40 KB x 4 blocks).
// Phase 1: 16 chunks of 64 s-rows staged via ONE 8 KB global_load_lds issue
//   (linear dest + involution-swizzled source); wave w = (qt = w>>2,
//   sw = w&3) computes s-tile g*4+sw for q-tile qt (2 MFMA over hd=64);
//   scores -> f16 LDS (64 KB, row-XOR-swizzled).
// Phase 2: wave-per-row softmax (rows rr*8+w), PLAIN coalesced f32x4 bias
//   read + out write.
// ---------------------------------------------------------------------------
__global__ __launch_bounds__(512) void attn_softmax(
    const u16* __restrict__ Qh, const u16* __restrict__ Kh,
    const float* __restrict__ bias, float* __restrict__ out)
{
  __shared__ __align__(16) char scb[32*2048];    // 64 KB f16 scores, swizzled
  __shared__ __align__(16) char kbuf[8192];      // 64 s-rows x 64 d, swizzled
  const int t = threadIdx.x;
  const int lane = t & 63;
  const int w = t >> 6;          // 0..7
  const int qt = w >> 2;         // q-tile 0/1
  const int sw = w & 3;          // s-tile within chunk
  const int ltile = blockIdx.x;  // 32 tiles of 32 q-rows
  const int b = blockIdx.y;      // 128 batch-heads

  const char* Kb = (const char*)(Kh + (size_t)b*65536);                 // 128 KB
  const u16*  Qb = Qh + (size_t)b*65536 + (size_t)ltile*32*64;          // 4 KB

  // A-frags: q-row = qt*16 + (lane&15), d = (lane>>4)*8
  int qoff = (qt*16 + (lane&15))*64 + (lane>>4)*8;
  bf16x8 a0 = *(const bf16x8*)(Qb + qoff);
  bf16x8 a1 = *(const bf16x8*)(Qb + qoff + 32);

  const int rowBase = qt*16 + (lane>>4)*4;
  uint32_t kbase = (uint32_t)(uintptr_t)&kbuf[0];

  for (int g = 0; g < 16; ++g) {
    __syncthreads();   // previous chunk's readers done before overwrite
    {
      int o = t*16;                              // 512 threads x 16 B = 8 KB
      int src = o ^ (((o>>7)&7)<<4);             // inverse swizzle (involution)
      __builtin_amdgcn_global_load_lds(
          (const AS1 void*)(uintptr_t)(Kb + (size_t)g*8192 + src),
          (AS3 void*)(uintptr_t)(kbase + (w<<10)), 16, 0, 0);
    }
    __syncthreads();   // staging visible (compiler drains vmcnt before barrier)

    // wave w: s-tile st = g*4+sw, local rows r = sw*16 + (lane&15)
    int r = sw*16 + (lane&15);
    int byte0 = r*128 + ((lane>>4)*16);
    int swzk = (r&7)<<4;
    bf16x8 b0 = *(const bf16x8*)(kbuf + ((byte0      ) ^ swzk));
    bf16x8 b1 = *(const bf16x8*)(kbuf + ((byte0 + 64 ) ^ swzk));
    f32x4 acc = {0.f,0.f,0.f,0.f};
    acc = __builtin_amdgcn_mfma_f32_16x16x32_bf16(a0, b0, acc, 0,0,0);
    acc = __builtin_amdgcn_mfma_f32_16x16x32_bf16(a1, b1, acc, 0,0,0);

    int scol = g*64 + sw*16 + (lane & 15);       // global s index
    #pragma unroll
    for (int rr=0;rr<4;rr++) {
      int row = rowBase + rr;                    // q-row in [0,32)
      int byte = (row*2048 + scol*2) ^ ((row&7)<<4);
      *(f16*)(scb + byte) = (f16)acc[rr];
    }
  }
  __syncthreads();

  // Phase 2: wave w owns rows {w, w+8, w+16, w+24}
  #pragma unroll
  for (int rr=0;rr<4;rr++) {
    int row = rr*8 + w;
    int l_glob = ltile*32 + row;
    const float* brow = bias + ((size_t)b*1024 + l_glob)*1024;
    float*       orow = out  + ((size_t)b*1024 + l_glob)*1024;
    const int swz = (row&7)<<4;
    float v[16];
    float mx = -1e30f;
    #pragma unroll
    for (int it=0; it<2; ++it) {
      int cb = it*1024 + lane*16;                 // logical byte offset in row
      f16x8 s8 = *(const f16x8*)(scb + ((row*2048 + cb) ^ swz));
      int col = it*512 + lane*8;
      f32x4 b4a = *(const f32x4*)(brow + col);
      f32x4 b4b = *(const f32x4*)(brow + col + 4);
      #pragma unroll
      for (int j=0;j<4;j++) v[it*8+j]   = (float)s8[j]   + b4a[j];
      #pragma unroll
      for (int j=0;j<4;j++) v[it*8+4+j] = (float)s8[4+j] + b4b[j];
    }
    #pragma unroll
    for (int j=0;j<16;j++) mx = fmaxf(mx, v[j]);
    #pragma unroll
    for (int off=32; off>0; off>>=1) mx = fmaxf(mx, __shfl_xor(mx, off, 64));
    float sum = 0.f;
    #pragma unroll
    for (int j=0;j<16;j++) { v[j] = __expf(v[j]-mx); sum += v[j]; }
    #pragma unroll
    for (int off=32; off>0; off>>=1) sum += __shfl_xor(sum, off, 64);
    float inv = 1.0f / sum;
    #pragma unroll
    for (int it=0; it<2; ++it) {
      int col = it*512 + lane*8;
      f32x4 o4a = { v[it*8+0]*inv, v[it*8+1]*inv, v[it*8+2]*inv, v[it*8+3]*inv };
      f32x4 o4b = { v[it*8+4]*inv, v[it*8+5]*inv, v[it*8+6]*inv, v[it*8+7]*inv };
      *(f32x4*)(orow + col)     = o4a;
      *(f32x4*)(orow + col + 4) = o4b;
    }
  }
}

// ---------------------------------------------------------------------------
// Workspace layout (68 MB total):
//   qbf 16 MB | kbf 16 MB | wq 2 MB | wk 2 MB | Qh 16 MB | Kh 16 MB
// ---------------------------------------------------------------------------
extern "C" void kernel_launch(void* const* d_in, const int* in_sizes, int n_in,
                              void* d_out, int out_size, void* d_ws, size_t ws_size,
                              hipStream_t stream) {
  const float* query = (const float*)d_in[0];
  const float* key   = (const float*)d_in[1];
  const float* w     = (const float*)d_in[2];
  const float* bias  = (const float*)d_in[3];
  const float* abias = (const float*)d_in[4];
  float* out = (float*)d_out;

  char* ws = (char*)d_ws;
  const size_t QKB = (size_t)M_ROWS*E_DIM*2;  // 16 MB
  const size_t WB  = (size_t)E_DIM*E_DIM*2;   // 2 MB
  u16* qbf = (u16*)ws;  ws += QKB;
  u16* kbf = (u16*)ws;  ws += QKB;
  u16* wq  = (u16*)ws;  ws += WB;
  u16* wk  = (u16*)ws;  ws += WB;
  u16* Qh  = (u16*)ws;  ws += QKB;   // head-major [bh][l][d]
  u16* Kh  = (u16*)ws;  ws += QKB;   // head-major [bh][s][d]

  hipLaunchKernelGGL(convert_kernel, dim3(2048), dim3(256), 0, stream,
                     query, key, w, qbf, kbf, wq, wk);
  hipLaunchKernelGGL(proj_gemm, dim3(64, 8), dim3(256), 0, stream,
                     qbf, wq, bias, 0.125f, Qh);
  hipLaunchKernelGGL(proj_gemm, dim3(64, 8), dim3(256), 0, stream,
                     kbf, wk, bias + 1024, 1.0f, Kh);
  hipLaunchKernelGGL(attn_softmax, dim3(32, 128), dim3(512), 0, stream,
                     Qh, Kh, abias, out);
}